// Round 2
// baseline (9429.015 us; speedup 1.0000x reference)
//
#include <hip/hip_runtime.h>
#include <math.h>

// ---------------------------------------------------------------------------
// DyRes/CondConv AlexNet forward, fp32 end-to-end.
// Every conv is a single implicit-im2col GEMM with the expert mix folded into
// the K dimension. R2: software-pipelined K-loop (reg prefetch of tile k+1
// during compute of tile k), BK=32, incremental im2col decode, float4 epilogue.
// ---------------------------------------------------------------------------

__global__ __launch_bounds__(64)
void stats_kernel(const float* __restrict__ act, float* __restrict__ s,
                  int Bsz, int C, int HW, int cbhw, int use_std)
{
    int idx = blockIdx.x;           // b*C + c
    int b = idx / C, c = idx - b * C;
    size_t base = cbhw ? ((size_t)c * Bsz + b) : ((size_t)b * C + c);
    const float* p = act + base * HW;
    int lane = threadIdx.x;
    float sum = 0.f, sq = 0.f;
    for (int i = lane; i < HW; i += 64) { float v = p[i]; sum += v; sq += v * v; }
#pragma unroll
    for (int off = 32; off > 0; off >>= 1) {
        sum += __shfl_down(sum, off);
        sq  += __shfl_down(sq, off);
    }
    if (lane == 0) {
        float inv = 1.f / (float)HW;
        float mean = sum * inv;
        float var = sq * inv - mean * mean;
        float outv = mean;
        if (use_std) outv += sqrtf(fmaxf(var, 0.f));
        s[idx] = outv;
    }
}

// r[b,e] = softmax_e / sigmoid of (s[b,:] @ rw.T + rb), E = 3
__global__ __launch_bounds__(64)
void routing_kernel(const float* __restrict__ s, const float* __restrict__ rw,
                    const float* __restrict__ rb, float* __restrict__ r,
                    int C, int softmax_mode)
{
    int b = blockIdx.x;
    int lane = threadIdx.x;
    float d0 = 0.f, d1 = 0.f, d2 = 0.f;
    for (int c = lane; c < C; c += 64) {
        float sv = s[b * C + c];
        d0 += sv * rw[c];
        d1 += sv * rw[C + c];
        d2 += sv * rw[2 * C + c];
    }
#pragma unroll
    for (int off = 32; off > 0; off >>= 1) {
        d0 += __shfl_down(d0, off);
        d1 += __shfl_down(d1, off);
        d2 += __shfl_down(d2, off);
    }
    if (lane == 0) {
        d0 += rb[0]; d1 += rb[1]; d2 += rb[2];
        if (softmax_mode) {
            float mx = fmaxf(d0, fmaxf(d1, d2));
            float e0 = expf(d0 - mx), e1 = expf(d1 - mx), e2 = expf(d2 - mx);
            float inv = 1.f / (e0 + e1 + e2);
            r[b * 3 + 0] = e0 * inv;
            r[b * 3 + 1] = e1 * inv;
            r[b * 3 + 2] = e2 * inv;
        } else {
            r[b * 3 + 0] = 1.f / (1.f + expf(-d0));
            r[b * 3 + 1] = 1.f / (1.f + expf(-d1));
            r[b * 3 + 2] = 1.f / (1.f + expf(-d2));
        }
    }
}

// ---------------------------------------------------------------------------
// Tiled GEMM: C[M,N] = op(A)[M,Ktot] * op(B)[Ktot,N]
// 64x64 tile, BK=32, 4x4 microtile, register-prefetch pipelined.
// BMODE: 0 = plain B[k*N+n]
//        1 = implicit im2col from act [Ci,Bsz,H,W], scaled by r[b,e]
//        2 = implicit im2col from act [Bsz,Ci,H,W] (layer-1 input), r-scaled
// AEXPERT: A[m,kk] = dw[(e*M+m)*Kper + kq]  (experts concat along K)
// FULLDEC: per-element decode + K bounds guard (conv1: Ktot%32!=0, Kper%8!=0)
//          non-FULLDEC paths REQUIRE Ktot%32==0 (and Kper%8==0 for BMODE!=0).
// ---------------------------------------------------------------------------
template<int BMODE, int AEXPERT, int BIAS, int RELU, int TROUT, int FULLDEC>
__global__ __launch_bounds__(256)
void gemm_kernel(const float* __restrict__ A, const float* __restrict__ Bm,
                 const float* __restrict__ rptr, const float* __restrict__ bias,
                 float* __restrict__ Cout,
                 int M, int N, int Ktot, int Kper,
                 int Ci, int Bsz, int H, int W, int lgS, int lgOW, int stride)
{
    constexpr int BK = 32;
    __shared__ float As[BK * 68];   // [k][m], stride 68 (2-way-max on store, 16B aligned)
    __shared__ float Bs[BK * 64];   // [k][n]
    const int tid = threadIdx.x;
    const int bx = blockIdx.x, by = blockIdx.y;
    const int tx = tid & 15, ty = tid >> 4;
    const int tkA = tid & 15, tmA = tid >> 4;
    const int tnB = tid & 63, tkB = (tid >> 6) << 3;
    const int n0 = bx << 6;
    const int ngB = n0 + tnB;
    const int m0 = by << 6;
    float acc[4][4] = {{0.f}};

    // n-side conv indices are k-independent: hoist out of the K loop
    int bB = 0, ohs = 0, ows = 0;
    float rr0 = 0.f, rr1 = 0.f, rr2 = 0.f;
    long bOff = 0;
    int chanStride = 0;
    if (BMODE != 0) {
        bB = ngB >> lgS;
        int sidx = ngB & ((1 << lgS) - 1);
        ohs = (sidx >> lgOW) * stride - 1;
        ows = (sidx & ((1 << lgOW) - 1)) * stride - 1;
        rr0 = rptr[bB * 3 + 0];
        rr1 = rptr[bB * 3 + 1];
        rr2 = rptr[bB * 3 + 2];
        if (BMODE == 2) { chanStride = H * W;       bOff = (long)bB * Ci * H * W; }
        else            { chanStride = Bsz * H * W; bOff = (long)bB * H * W; }
    }

    float rA[2][4], rB[8];

    auto loadA = [&](int k0) {
#pragma unroll
        for (int h = 0; h < 2; ++h) {
            int kk = k0 + tkA + h * 16;
            int e = 0, kq = kk;
            if (AEXPERT) {
                e = (kk >= Kper) + (kk >= 2 * Kper);
                kq = kk - e * Kper;
            }
            size_t rowstride = (size_t)(AEXPERT ? Kper : Ktot);
            const float* ap = AEXPERT ? (A + (size_t)(e * M + m0 + tmA) * rowstride + kq)
                                      : (A + (size_t)(m0 + tmA) * rowstride + kk);
#pragma unroll
            for (int i = 0; i < 4; ++i) {
                float v = 0.f;
                bool ok = (m0 + tmA + i * 16) < M;
                if (FULLDEC) ok = ok && (kk < Ktot);
                if (ok) v = ap[(size_t)i * 16 * rowstride];
                rA[h][i] = v;
            }
        }
    };

    auto loadB = [&](int k0) {
        if (BMODE == 0) {
            const float* bp = Bm + (size_t)(k0 + tkB) * N + ngB;
#pragma unroll
            for (int j = 0; j < 8; ++j) rB[j] = bp[(size_t)j * N];
        } else if (FULLDEC) {
#pragma unroll
            for (int j = 0; j < 8; ++j) {
                int kk = k0 + tkB + j;
                float v = 0.f;
                if (kk < Ktot) {
                    int e = (kk >= Kper) + (kk >= 2 * Kper);
                    int kq = kk - e * Kper;
                    int ci = kq / 9;
                    int r9 = kq - ci * 9;
                    int kh = r9 / 3;
                    int kw = r9 - kh * 3;
                    int ih = ohs + kh, iw = ows + kw;
                    if ((unsigned)ih < (unsigned)H && (unsigned)iw < (unsigned)W) {
                        float rs = (e == 0) ? rr0 : ((e == 1) ? rr1 : rr2);
                        v = Bm[bOff + (long)ci * chanStride + ih * W + iw] * rs;
                    }
                }
                rB[j] = v;
            }
        } else {
            // thread's 8 consecutive k stay within one expert (Kper % 8 == 0)
            int kk0 = k0 + tkB;
            int e = (kk0 >= Kper) + (kk0 >= 2 * Kper);
            int kq = kk0 - e * Kper;
            int ci = kq / 9;
            int r9 = kq - ci * 9;
            int kh = r9 / 3;
            int kw = r9 - kh * 3;
            float rs = (e == 0) ? rr0 : ((e == 1) ? rr1 : rr2);
            long choff = bOff + (long)ci * chanStride;
#pragma unroll
            for (int j = 0; j < 8; ++j) {
                int ih = ohs + kh, iw = ows + kw;
                float v = 0.f;
                if ((unsigned)ih < (unsigned)H && (unsigned)iw < (unsigned)W)
                    v = Bm[choff + ih * W + iw];
                rB[j] = v * rs;
                if (++kw == 3) { kw = 0; if (++kh == 3) { kh = 0; choff += chanStride; } }
            }
        }
    };

    auto storeLDS = [&]() {
#pragma unroll
        for (int h = 0; h < 2; ++h)
#pragma unroll
            for (int i = 0; i < 4; ++i)
                As[(tkA + h * 16) * 68 + tmA + i * 16] = rA[h][i];
#pragma unroll
        for (int j = 0; j < 8; ++j)
            Bs[(tkB + j) * 64 + tnB] = rB[j];
    };

    auto compute = [&]() {
#pragma unroll
        for (int k = 0; k < BK; ++k) {
            float4 av = *(const float4*)(&As[k * 68 + (ty << 2)]);
            float4 bv = *(const float4*)(&Bs[(k << 6) + (tx << 2)]);
            float a4[4] = {av.x, av.y, av.z, av.w};
            float b4[4] = {bv.x, bv.y, bv.z, bv.w};
#pragma unroll
            for (int i = 0; i < 4; ++i)
#pragma unroll
                for (int j = 0; j < 4; ++j)
                    acc[i][j] = fmaf(a4[i], b4[j], acc[i][j]);
        }
    };

    // ---- pipelined main loop ----
    loadA(0); loadB(0);
    storeLDS();
    __syncthreads();
    for (int k0 = BK; k0 < Ktot; k0 += BK) {
        loadA(k0); loadB(k0);       // prefetch next tile into regs (overlaps compute)
        compute();
        __syncthreads();
        storeLDS();                 // vmcnt wait lands here, after compute
        __syncthreads();
    }
    compute();

    // ---- epilogue ----
#pragma unroll
    for (int i = 0; i < 4; ++i) {
        int mg = m0 + (ty << 2) + i;
        if (mg >= M) continue;
        float bv = BIAS ? bias[mg] : 0.f;
        if (!TROUT) {
            // N is a multiple of 64 for all non-TROUT layers -> aligned float4
            float4 v;
            v.x = acc[i][0] + bv; v.y = acc[i][1] + bv;
            v.z = acc[i][2] + bv; v.w = acc[i][3] + bv;
            if (RELU) {
                v.x = fmaxf(v.x, 0.f); v.y = fmaxf(v.y, 0.f);
                v.z = fmaxf(v.z, 0.f); v.w = fmaxf(v.w, 0.f);
            }
            *(float4*)(&Cout[(size_t)mg * N + n0 + (tx << 2)]) = v;
        } else {
#pragma unroll
            for (int j = 0; j < 4; ++j) {
                int ng = n0 + (tx << 2) + j;
                float v = acc[i][j] + bv;
                if (RELU) v = fmaxf(v, 0.f);
                Cout[(size_t)ng * M + mg] = v;   // out[b*M + m]
            }
        }
    }
}

// 2x2/2 maxpool on [CB, H, W] -> [CB, H/2, W/2]
__global__ __launch_bounds__(256)
void pool_kernel(const float* __restrict__ in, float* __restrict__ out,
                 int CB, int H, int W)
{
    int OH = H >> 1, OW = W >> 1;
    int total = CB * OH * OW;
    int i = blockIdx.x * 256 + threadIdx.x;
    if (i >= total) return;
    int ow = i % OW;
    int t = i / OW;
    int oh = t % OH;
    int cb = t / OH;
    const float* p = in + ((size_t)cb * H + (oh << 1)) * W + (ow << 1);
    out[i] = fmaxf(fmaxf(p[0], p[1]), fmaxf(p[W], p[W + 1]));
}

// conv5 out [256,512,4,4] --pool2x2--> flatten to hT [1024, 512] (feature-major)
__global__ __launch_bounds__(256)
void pool_flatten_kernel(const float* __restrict__ in, float* __restrict__ out)
{
    int i = blockIdx.x * 256 + threadIdx.x;     // over 256*512*4
    if (i >= 256 * 512 * 4) return;
    int b = i & 511;
    int t = i >> 9;
    int s = t & 3;          // oh*2+ow of pooled 2x2
    int c = t >> 2;
    int oh = s >> 1, ow = s & 1;
    const float* p = in + (((size_t)c * 512 + b) * 4 + (oh << 1)) * 4 + (ow << 1);
    float v = fmaxf(fmaxf(p[0], p[1]), fmaxf(p[4], p[5]));
    out[(size_t)(c * 4 + s) * 512 + b] = v;
}

extern "C" void kernel_launch(void* const* d_in, const int* in_sizes, int n_in,
                              void* d_out, int out_size, void* d_ws, size_t ws_size,
                              hipStream_t stream)
{
    const float* x    = (const float*)d_in[0];
    const float* dw1  = (const float*)d_in[1];
    const float* rw1  = (const float*)d_in[2];
    const float* rb1  = (const float*)d_in[3];
    const float* dw2  = (const float*)d_in[4];
    const float* rw2  = (const float*)d_in[5];
    const float* rb2  = (const float*)d_in[6];
    const float* dw3  = (const float*)d_in[7];
    const float* rw3  = (const float*)d_in[8];
    const float* rb3  = (const float*)d_in[9];
    const float* cw4  = (const float*)d_in[10];
    const float* cr4w = (const float*)d_in[11];
    const float* cr4b = (const float*)d_in[12];
    const float* cw5  = (const float*)d_in[13];
    const float* cr5w = (const float*)d_in[14];
    const float* cr5b = (const float*)d_in[15];
    const float* fw1  = (const float*)d_in[16];
    const float* fb1  = (const float*)d_in[17];
    const float* fw2  = (const float*)d_in[18];
    const float* fb2  = (const float*)d_in[19];
    const float* fw3  = (const float*)d_in[20];
    const float* fb3  = (const float*)d_in[21];
    float* out = (float*)d_out;

    // workspace layout (floats); total ~14.9M floats = ~60 MB
    float* ws    = (float*)d_ws;
    float* r1    = ws;
    float* r2    = r1 + 1536;
    float* r3    = r2 + 1536;
    float* r4    = r3 + 1536;
    float* r5    = r4 + 1536;
    float* sdesc = ws + 8192;               // 512*384 max
    float* slabA = sdesc + 196608;          // 8,388,608 floats (c1/c2/c3/c5)
    float* slabB = slabA + 8388608;         // 2,097,152 floats (c4/fc1)
    float* a1    = slabB + 2097152;         // 2,097,152 (pooled1; later fc2 out)
    float* a2    = a1 + 2097152;            // 1,572,864 (pooled2)
    float* hT    = a2 + 1572864;            // 524,288

    const int B = 512;

    // ---- Layer 1: DyRes conv 3->64, stride 2, pad 1 -> c1 [64, 512*16*16] ----
    stats_kernel<<<B * 3, 64, 0, stream>>>(x, sdesc, B, 3, 1024, 0, 1);
    routing_kernel<<<B, 64, 0, stream>>>(sdesc, rw1, rb1, r1, 3, 1);
    gemm_kernel<2, 1, 0, 1, 0, 1><<<dim3(131072 / 64, 1), 256, 0, stream>>>(
        dw1, x, r1, nullptr, slabA, 64, 131072, 81, 27, 3, B, 32, 32, 8, 4, 2);
    pool_kernel<<<(64 * 512 * 64) / 256, 256, 0, stream>>>(slabA, a1, 64 * 512, 16, 16);

    // ---- Layer 2: DyRes conv 64->192 -> c2 [192, 512*8*8] ----
    stats_kernel<<<B * 64, 64, 0, stream>>>(a1, sdesc, B, 64, 64, 1, 1);
    routing_kernel<<<B, 64, 0, stream>>>(sdesc, rw2, rb2, r2, 64, 1);
    gemm_kernel<1, 1, 0, 1, 0, 0><<<dim3(32768 / 64, 3), 256, 0, stream>>>(
        dw2, a1, r2, nullptr, slabA, 192, 32768, 1728, 576, 64, B, 8, 8, 6, 3, 1);
    pool_kernel<<<(192 * 512 * 16) / 256, 256, 0, stream>>>(slabA, a2, 192 * 512, 8, 8);

    // ---- Layer 3: DyRes conv 192->384 -> c3 [384, 512*4*4] ----
    stats_kernel<<<B * 192, 64, 0, stream>>>(a2, sdesc, B, 192, 16, 1, 1);
    routing_kernel<<<B, 64, 0, stream>>>(sdesc, rw3, rb3, r3, 192, 1);
    gemm_kernel<1, 1, 0, 1, 0, 0><<<dim3(8192 / 64, 6), 256, 0, stream>>>(
        dw3, a2, r3, nullptr, slabA, 384, 8192, 5184, 1728, 192, B, 4, 4, 4, 2, 1);

    // ---- Layer 4: CondConv 384->256 -> c4 [256, 8192] (reads slabA, writes slabB) ----
    stats_kernel<<<B * 384, 64, 0, stream>>>(slabA, sdesc, B, 384, 16, 1, 0);
    routing_kernel<<<B, 64, 0, stream>>>(sdesc, cr4w, cr4b, r4, 384, 0);
    gemm_kernel<1, 1, 0, 1, 0, 0><<<dim3(8192 / 64, 4), 256, 0, stream>>>(
        cw4, slabA, r4, nullptr, slabB, 256, 8192, 10368, 3456, 384, B, 4, 4, 4, 2, 1);

    // ---- Layer 5: CondConv 256->256 -> c5 [256, 8192] (reads slabB, writes slabA) ----
    stats_kernel<<<B * 256, 64, 0, stream>>>(slabB, sdesc, B, 256, 16, 1, 0);
    routing_kernel<<<B, 64, 0, stream>>>(sdesc, cr5w, cr5b, r5, 256, 0);
    gemm_kernel<1, 1, 0, 1, 0, 0><<<dim3(8192 / 64, 4), 256, 0, stream>>>(
        cw5, slabB, r5, nullptr, slabA, 256, 8192, 6912, 2304, 256, B, 4, 4, 4, 2, 1);

    // ---- pool + flatten -> hT [1024, 512] ----
    pool_flatten_kernel<<<(256 * 512 * 4) / 256, 256, 0, stream>>>(slabA, hT);

    // ---- FC1: 1024 -> 4096, relu -> slabB [4096, 512] ----
    gemm_kernel<0, 0, 1, 1, 0, 0><<<dim3(8, 64), 256, 0, stream>>>(
        fw1, hT, nullptr, fb1, slabB, 4096, 512, 1024, 0, 0, 0, 0, 0, 0, 0, 0);
    // ---- FC2: 4096 -> 4096, relu -> a1 [4096, 512] ----
    gemm_kernel<0, 0, 1, 1, 0, 0><<<dim3(8, 64), 256, 0, stream>>>(
        fw2, slabB, nullptr, fb2, a1, 4096, 512, 4096, 0, 0, 0, 0, 0, 0, 0, 0);
    // ---- FC3: 4096 -> 100, transposed store into d_out [512, 100] ----
    gemm_kernel<0, 0, 1, 0, 1, 0><<<dim3(8, 2), 256, 0, stream>>>(
        fw3, a1, nullptr, fb3, out, 100, 512, 4096, 0, 0, 0, 0, 0, 0, 0, 0);
}

// Round 3
// 4412.604 us; speedup vs baseline: 2.1368x; 2.1368x over previous
//
#include <hip/hip_runtime.h>
#include <math.h>

// ---------------------------------------------------------------------------
// DyRes/CondConv AlexNet forward, fp32 end-to-end.
// Every conv is an implicit-im2col GEMM with the expert mix folded into K.
// R3: revert to R1's proven low-VGPR synchronous GEMM body (R2's register
// prefetch spilled: WRITE_SIZE 8->176MB). Add split-K (per-expert for convs,
// K-chunks for FCs) with fp32 atomicAdd partials to raise occupancy 2->6-9
// blocks/CU on the deep-K layers. Relu moved to tiny elementwise/pool passes.
// ---------------------------------------------------------------------------

__global__ __launch_bounds__(64)
void stats_kernel(const float* __restrict__ act, float* __restrict__ s,
                  int Bsz, int C, int HW, int cbhw, int use_std)
{
    int idx = blockIdx.x;           // b*C + c
    int b = idx / C, c = idx - b * C;
    size_t base = cbhw ? ((size_t)c * Bsz + b) : ((size_t)b * C + c);
    const float* p = act + base * HW;
    int lane = threadIdx.x;
    float sum = 0.f, sq = 0.f;
    for (int i = lane; i < HW; i += 64) { float v = p[i]; sum += v; sq += v * v; }
#pragma unroll
    for (int off = 32; off > 0; off >>= 1) {
        sum += __shfl_down(sum, off);
        sq  += __shfl_down(sq, off);
    }
    if (lane == 0) {
        float inv = 1.f / (float)HW;
        float mean = sum * inv;
        float var = sq * inv - mean * mean;
        float outv = mean;
        if (use_std) outv += sqrtf(fmaxf(var, 0.f));
        s[idx] = outv;
    }
}

// r[b,e] = softmax_e / sigmoid of (s[b,:] @ rw.T + rb), E = 3
__global__ __launch_bounds__(64)
void routing_kernel(const float* __restrict__ s, const float* __restrict__ rw,
                    const float* __restrict__ rb, float* __restrict__ r,
                    int C, int softmax_mode)
{
    int b = blockIdx.x;
    int lane = threadIdx.x;
    float d0 = 0.f, d1 = 0.f, d2 = 0.f;
    for (int c = lane; c < C; c += 64) {
        float sv = s[b * C + c];
        d0 += sv * rw[c];
        d1 += sv * rw[C + c];
        d2 += sv * rw[2 * C + c];
    }
#pragma unroll
    for (int off = 32; off > 0; off >>= 1) {
        d0 += __shfl_down(d0, off);
        d1 += __shfl_down(d1, off);
        d2 += __shfl_down(d2, off);
    }
    if (lane == 0) {
        d0 += rb[0]; d1 += rb[1]; d2 += rb[2];
        if (softmax_mode) {
            float mx = fmaxf(d0, fmaxf(d1, d2));
            float e0 = expf(d0 - mx), e1 = expf(d1 - mx), e2 = expf(d2 - mx);
            float inv = 1.f / (e0 + e1 + e2);
            r[b * 3 + 0] = e0 * inv;
            r[b * 3 + 1] = e1 * inv;
            r[b * 3 + 2] = e2 * inv;
        } else {
            r[b * 3 + 0] = 1.f / (1.f + expf(-d0));
            r[b * 3 + 1] = 1.f / (1.f + expf(-d1));
            r[b * 3 + 2] = 1.f / (1.f + expf(-d2));
        }
    }
}

// ---------------------------------------------------------------------------
// Tiled GEMM: C[M,N] (+)= op(A)[M,k-range] * op(B)[k-range,N]
// 64x64 tile, BK=16, 4x4 microtile, R1 synchronous body (44 VGPR).
// blockIdx.z selects the K chunk: [z*Kchunk, min((z+1)*Kchunk, Ktot)).
// BMODE: 0 = plain B[k*N+n]
//        1 = implicit im2col from act [Ci,Bsz,H,W], scaled by r[b,e]
//        2 = implicit im2col from act [Bsz,Ci,H,W] (layer-1 input), r-scaled
// AEXPERT: A[m,kk] = dw[(e*M+m)*Kper + kq]  (experts concat along K)
// ATOMIC: epilogue atomicAdd into Cout (dest must be pre-zeroed); bias added
//         only by the z==0 chunk; RELU must be 0 in atomic mode.
// ---------------------------------------------------------------------------
template<int BMODE, int AEXPERT, int BIAS, int RELU, int TROUT, int ATOMIC>
__global__ __launch_bounds__(256)
void gemm_kernel(const float* __restrict__ A, const float* __restrict__ Bm,
                 const float* __restrict__ rptr, const float* __restrict__ bias,
                 float* __restrict__ Cout,
                 int M, int N, int Ktot, int Kper, int Kchunk,
                 int Ci, int Bsz, int H, int W, int lgS, int lgOW, int stride)
{
    __shared__ float As[16 * 68];   // [k][m], stride 68
    __shared__ float Bs[16 * 64];   // [k][n]
    const int tid = threadIdx.x;
    const int bx = blockIdx.x, by = blockIdx.y, bz = blockIdx.z;
    const int tx = tid & 15, ty = tid >> 4;
    const int tk = tid & 15, tm0 = tid >> 4;
    const int tn = tid & 63, tkb = tid >> 6;
    const int n0 = bx << 6;
    const int ngB = n0 + tn;
    const int m0 = by << 6;
    const int kBeg = bz * Kchunk;
    const int kEnd = min(kBeg + Kchunk, Ktot);
    float acc[4][4] = {{0.f}};

    // n-side conv indices are k-independent: hoist out of the K loop
    int bB = 0, ohB = 0, owB = 0;
    float rB0 = 0.f, rB1 = 0.f, rB2 = 0.f;
    if (BMODE != 0) {
        bB = ngB >> lgS;
        int sidx = ngB & ((1 << lgS) - 1);
        ohB = sidx >> lgOW;
        owB = sidx & ((1 << lgOW) - 1);
        rB0 = rptr[bB * 3 + 0];
        rB1 = rptr[bB * 3 + 1];
        rB2 = rptr[bB * 3 + 2];
    }

    for (int k0 = kBeg; k0 < kEnd; k0 += 16) {
        // ---- stage A tile ----
        {
            int kk = k0 + tk;
            int e = 0, kq = kk;
            if (AEXPERT) {
                e = (kk >= Kper) + (kk >= 2 * Kper);
                kq = kk - e * Kper;
            }
#pragma unroll
            for (int i = 0; i < 4; ++i) {
                int m = tm0 + i * 16;
                int mg = m0 + m;
                float v = 0.f;
                if (kk < kEnd && mg < M) {
                    if (AEXPERT) v = A[((size_t)(e * M + mg)) * Kper + kq];
                    else         v = A[(size_t)mg * Ktot + kk];
                }
                As[tk * 68 + m] = v;
            }
        }
        // ---- stage B tile ----
#pragma unroll
        for (int j = 0; j < 4; ++j) {
            int kloc = (tkb << 2) + j;
            int kk = k0 + kloc;
            float v = 0.f;
            if (kk < kEnd) {
                if (BMODE == 0) {
                    v = Bm[(size_t)kk * N + ngB];
                } else {
                    int e = (kk >= Kper) + (kk >= 2 * Kper);
                    int kq = kk - e * Kper;
                    int ci = kq / 9;
                    int rrem = kq - ci * 9;
                    int kh = rrem / 3;
                    int kw = rrem - kh * 3;
                    int ih = ohB * stride - 1 + kh;
                    int iw = owB * stride - 1 + kw;
                    if ((unsigned)ih < (unsigned)H && (unsigned)iw < (unsigned)W) {
                        size_t aidx;
                        if (BMODE == 2) aidx = (((size_t)bB * Ci + ci) * H + ih) * W + iw;
                        else            aidx = (((size_t)ci * Bsz + bB) * H + ih) * W + iw;
                        float rs = (e == 0) ? rB0 : ((e == 1) ? rB1 : rB2);
                        v = Bm[aidx] * rs;
                    }
                }
            }
            Bs[kloc * 64 + tn] = v;
        }
        __syncthreads();
        // ---- compute ----
#pragma unroll
        for (int k = 0; k < 16; ++k) {
            float4 av = *(const float4*)(&As[k * 68 + (ty << 2)]);
            float4 bv = *(const float4*)(&Bs[(k << 6) + (tx << 2)]);
            float a4[4] = {av.x, av.y, av.z, av.w};
            float b4[4] = {bv.x, bv.y, bv.z, bv.w};
#pragma unroll
            for (int i = 0; i < 4; ++i)
#pragma unroll
                for (int j = 0; j < 4; ++j)
                    acc[i][j] = fmaf(a4[i], b4[j], acc[i][j]);
        }
        __syncthreads();
    }

    // ---- epilogue ----
#pragma unroll
    for (int i = 0; i < 4; ++i) {
        int mg = m0 + (ty << 2) + i;
        if (mg >= M) continue;
        float bv = (BIAS && kBeg == 0) ? bias[mg] : 0.f;
        if (ATOMIC) {
#pragma unroll
            for (int j = 0; j < 4; ++j) {
                int ng = n0 + (tx << 2) + j;
                if (ng >= N) continue;
                float v = acc[i][j] + bv;
                if (TROUT) atomicAdd(&Cout[(size_t)ng * M + mg], v);
                else       atomicAdd(&Cout[(size_t)mg * N + ng], v);
            }
        } else if (!TROUT) {
            float4 v;
            v.x = acc[i][0] + bv; v.y = acc[i][1] + bv;
            v.z = acc[i][2] + bv; v.w = acc[i][3] + bv;
            if (RELU) {
                v.x = fmaxf(v.x, 0.f); v.y = fmaxf(v.y, 0.f);
                v.z = fmaxf(v.z, 0.f); v.w = fmaxf(v.w, 0.f);
            }
            *(float4*)(&Cout[(size_t)mg * N + n0 + (tx << 2)]) = v;
        } else {
#pragma unroll
            for (int j = 0; j < 4; ++j) {
                int ng = n0 + (tx << 2) + j;
                if (ng >= N) continue;
                float v = acc[i][j] + bv;
                if (RELU) v = fmaxf(v, 0.f);
                Cout[(size_t)ng * M + mg] = v;
            }
        }
    }
}

// elementwise relu in place, float4, count % 1024 == 0
__global__ __launch_bounds__(256)
void relu_kernel(float* __restrict__ p, int count4)
{
    int i = blockIdx.x * 256 + threadIdx.x;
    if (i >= count4) return;
    float4 v = ((const float4*)p)[i];
    v.x = fmaxf(v.x, 0.f); v.y = fmaxf(v.y, 0.f);
    v.z = fmaxf(v.z, 0.f); v.w = fmaxf(v.w, 0.f);
    ((float4*)p)[i] = v;
}

// 2x2/2 maxpool on [CB, H, W] -> [CB, H/2, W/2]
__global__ __launch_bounds__(256)
void pool_kernel(const float* __restrict__ in, float* __restrict__ out,
                 int CB, int H, int W)
{
    int OH = H >> 1, OW = W >> 1;
    int total = CB * OH * OW;
    int i = blockIdx.x * 256 + threadIdx.x;
    if (i >= total) return;
    int ow = i % OW;
    int t = i / OW;
    int oh = t % OH;
    int cb = t / OH;
    const float* p = in + ((size_t)cb * H + (oh << 1)) * W + (ow << 1);
    out[i] = fmaxf(fmaxf(p[0], p[1]), fmaxf(p[W], p[W + 1]));
}

// conv5 out [256,512,4,4] --relu+pool2x2--> hT [1024, 512] (feature-major)
// relu commutes with max; conv5 is atomic-accumulated so relu lands here.
__global__ __launch_bounds__(256)
void pool_flatten_kernel(const float* __restrict__ in, float* __restrict__ out)
{
    int i = blockIdx.x * 256 + threadIdx.x;     // over 256*512*4
    if (i >= 256 * 512 * 4) return;
    int b = i & 511;
    int t = i >> 9;
    int s = t & 3;          // oh*2+ow of pooled 2x2
    int c = t >> 2;
    int oh = s >> 1, ow = s & 1;
    const float* p = in + (((size_t)c * 512 + b) * 4 + (oh << 1)) * 4 + (ow << 1);
    float v = fmaxf(fmaxf(p[0], p[1]), fmaxf(p[4], p[5]));
    out[(size_t)(c * 4 + s) * 512 + b] = fmaxf(v, 0.f);
}

extern "C" void kernel_launch(void* const* d_in, const int* in_sizes, int n_in,
                              void* d_out, int out_size, void* d_ws, size_t ws_size,
                              hipStream_t stream)
{
    const float* x    = (const float*)d_in[0];
    const float* dw1  = (const float*)d_in[1];
    const float* rw1  = (const float*)d_in[2];
    const float* rb1  = (const float*)d_in[3];
    const float* dw2  = (const float*)d_in[4];
    const float* rw2  = (const float*)d_in[5];
    const float* rb2  = (const float*)d_in[6];
    const float* dw3  = (const float*)d_in[7];
    const float* rw3  = (const float*)d_in[8];
    const float* rb3  = (const float*)d_in[9];
    const float* cw4  = (const float*)d_in[10];
    const float* cr4w = (const float*)d_in[11];
    const float* cr4b = (const float*)d_in[12];
    const float* cw5  = (const float*)d_in[13];
    const float* cr5w = (const float*)d_in[14];
    const float* cr5b = (const float*)d_in[15];
    const float* fw1  = (const float*)d_in[16];
    const float* fb1  = (const float*)d_in[17];
    const float* fw2  = (const float*)d_in[18];
    const float* fb2  = (const float*)d_in[19];
    const float* fw3  = (const float*)d_in[20];
    const float* fb3  = (const float*)d_in[21];
    float* out = (float*)d_out;

    // workspace layout (floats); total ~14.9M floats = ~60 MB
    float* ws    = (float*)d_ws;
    float* r1    = ws;
    float* r2    = r1 + 1536;
    float* r3    = r2 + 1536;
    float* r4    = r3 + 1536;
    float* r5    = r4 + 1536;
    float* sdesc = ws + 8192;               // 512*384 max
    float* slabA = sdesc + 196608;          // 8,388,608 floats (c1/c2/c3/c5)
    float* slabB = slabA + 8388608;         // 2,097,152 floats (c4/fc1)
    float* a1    = slabB + 2097152;         // 2,097,152 (pooled1; later fc2 out)
    float* a2    = a1 + 2097152;            // 1,572,864 (pooled2)
    float* hT    = a2 + 1572864;            // 524,288

    const int B = 512;

    // ---- Layer 1: DyRes conv 3->64, s2 p1 -> c1 [64, 512*16*16] (direct, relu) ----
    stats_kernel<<<B * 3, 64, 0, stream>>>(x, sdesc, B, 3, 1024, 0, 1);
    routing_kernel<<<B, 64, 0, stream>>>(sdesc, rw1, rb1, r1, 3, 1);
    gemm_kernel<2, 1, 0, 1, 0, 0><<<dim3(2048, 1, 1), 256, 0, stream>>>(
        dw1, x, r1, nullptr, slabA, 64, 131072, 81, 27, 81, 3, B, 32, 32, 8, 4, 2);
    pool_kernel<<<(64 * 512 * 64) / 256, 256, 0, stream>>>(slabA, a1, 64 * 512, 16, 16);

    // ---- Layer 2: DyRes conv 64->192 -> c2 [192, 32768] (direct, relu; 1536 blocks) ----
    stats_kernel<<<B * 64, 64, 0, stream>>>(a1, sdesc, B, 64, 64, 1, 1);
    routing_kernel<<<B, 64, 0, stream>>>(sdesc, rw2, rb2, r2, 64, 1);
    gemm_kernel<1, 1, 0, 1, 0, 0><<<dim3(512, 3, 1), 256, 0, stream>>>(
        dw2, a1, r2, nullptr, slabA, 192, 32768, 1728, 576, 1728, 64, B, 8, 8, 6, 3, 1);
    pool_kernel<<<(192 * 512 * 16) / 256, 256, 0, stream>>>(slabA, a2, 192 * 512, 8, 8);

    // ---- Layer 3: DyRes conv 192->384 -> c3 [384, 8192] (split-K x3 atomic) ----
    stats_kernel<<<B * 192, 64, 0, stream>>>(a2, sdesc, B, 192, 16, 1, 1);
    routing_kernel<<<B, 64, 0, stream>>>(sdesc, rw3, rb3, r3, 192, 1);
    hipMemsetAsync(slabA, 0, (size_t)384 * 8192 * 4, stream);
    gemm_kernel<1, 1, 0, 0, 0, 1><<<dim3(128, 6, 3), 256, 0, stream>>>(
        dw3, a2, r3, nullptr, slabA, 384, 8192, 5184, 1728, 1728, 192, B, 4, 4, 4, 2, 1);
    relu_kernel<<<(384 * 8192 / 4) / 256, 256, 0, stream>>>(slabA, 384 * 8192 / 4);

    // ---- Layer 4: CondConv 384->256 -> c4 [256, 8192] (split-K x3 atomic) ----
    stats_kernel<<<B * 384, 64, 0, stream>>>(slabA, sdesc, B, 384, 16, 1, 0);
    routing_kernel<<<B, 64, 0, stream>>>(sdesc, cr4w, cr4b, r4, 384, 0);
    hipMemsetAsync(slabB, 0, (size_t)256 * 8192 * 4, stream);
    gemm_kernel<1, 1, 0, 0, 0, 1><<<dim3(128, 4, 3), 256, 0, stream>>>(
        cw4, slabA, r4, nullptr, slabB, 256, 8192, 10368, 3456, 3456, 384, B, 4, 4, 4, 2, 1);
    relu_kernel<<<(256 * 8192 / 4) / 256, 256, 0, stream>>>(slabB, 256 * 8192 / 4);

    // ---- Layer 5: CondConv 256->256 -> c5 [256, 8192] (split-K x3 atomic) ----
    stats_kernel<<<B * 256, 64, 0, stream>>>(slabB, sdesc, B, 256, 16, 1, 0);
    routing_kernel<<<B, 64, 0, stream>>>(sdesc, cr5w, cr5b, r5, 256, 0);
    hipMemsetAsync(slabA, 0, (size_t)256 * 8192 * 4, stream);
    gemm_kernel<1, 1, 0, 0, 0, 1><<<dim3(128, 4, 3), 256, 0, stream>>>(
        cw5, slabB, r5, nullptr, slabA, 256, 8192, 6912, 2304, 2304, 256, B, 4, 4, 4, 2, 1);

    // ---- relu + pool + flatten -> hT [1024, 512] ----
    pool_flatten_kernel<<<(256 * 512 * 4) / 256, 256, 0, stream>>>(slabA, hT);

    // ---- FC1: 1024 -> 4096 (split-K x4 atomic, 2048 blocks), then relu ----
    hipMemsetAsync(slabB, 0, (size_t)4096 * 512 * 4, stream);
    gemm_kernel<0, 0, 1, 0, 0, 1><<<dim3(8, 64, 4), 256, 0, stream>>>(
        fw1, hT, nullptr, fb1, slabB, 4096, 512, 1024, 0, 256, 0, 0, 0, 0, 0, 0, 0);
    relu_kernel<<<(4096 * 512 / 4) / 256, 256, 0, stream>>>(slabB, 4096 * 512 / 4);

    // ---- FC2: 4096 -> 4096 (split-K x4 atomic, 2048 blocks), then relu ----
    hipMemsetAsync(a1, 0, (size_t)4096 * 512 * 4, stream);
    gemm_kernel<0, 0, 1, 0, 0, 1><<<dim3(8, 64, 4), 256, 0, stream>>>(
        fw2, slabB, nullptr, fb2, a1, 4096, 512, 4096, 0, 1024, 0, 0, 0, 0, 0, 0, 0);
    relu_kernel<<<(4096 * 512 / 4) / 256, 256, 0, stream>>>(a1, 4096 * 512 / 4);

    // ---- FC3: 4096 -> 100 (split-K x16 atomic, transposed into d_out) ----
    hipMemsetAsync(out, 0, (size_t)512 * 100 * 4, stream);
    gemm_kernel<0, 0, 1, 0, 1, 1><<<dim3(8, 2, 16), 256, 0, stream>>>(
        fw3, a1, nullptr, fb3, out, 100, 512, 4096, 0, 256, 0, 0, 0, 0, 0, 0, 0);
}

// Round 4
// 4368.145 us; speedup vs baseline: 2.1586x; 1.0102x over previous
//
#include <hip/hip_runtime.h>
#include <math.h>

// ---------------------------------------------------------------------------
// DyRes/CondConv AlexNet forward, fp32 end-to-end.
// Every conv is an implicit-im2col GEMM with the expert mix folded into K.
// R4: widen GEMM tile to 64x128 (4x8 microtile, 256 thr) to double FMA per
// LDS byte; keep R3's proven synchronous BK=16 body + split-K atomics.
// B-fragment read as two float4 groups (tx*4, 64+tx*4) to stay 2-way-free.
// ---------------------------------------------------------------------------

__global__ __launch_bounds__(64)
void stats_kernel(const float* __restrict__ act, float* __restrict__ s,
                  int Bsz, int C, int HW, int cbhw, int use_std)
{
    int idx = blockIdx.x;           // b*C + c
    int b = idx / C, c = idx - b * C;
    size_t base = cbhw ? ((size_t)c * Bsz + b) : ((size_t)b * C + c);
    const float* p = act + base * HW;
    int lane = threadIdx.x;
    float sum = 0.f, sq = 0.f;
    for (int i = lane; i < HW; i += 64) { float v = p[i]; sum += v; sq += v * v; }
#pragma unroll
    for (int off = 32; off > 0; off >>= 1) {
        sum += __shfl_down(sum, off);
        sq  += __shfl_down(sq, off);
    }
    if (lane == 0) {
        float inv = 1.f / (float)HW;
        float mean = sum * inv;
        float var = sq * inv - mean * mean;
        float outv = mean;
        if (use_std) outv += sqrtf(fmaxf(var, 0.f));
        s[idx] = outv;
    }
}

// r[b,e] = softmax_e / sigmoid of (s[b,:] @ rw.T + rb), E = 3
__global__ __launch_bounds__(64)
void routing_kernel(const float* __restrict__ s, const float* __restrict__ rw,
                    const float* __restrict__ rb, float* __restrict__ r,
                    int C, int softmax_mode)
{
    int b = blockIdx.x;
    int lane = threadIdx.x;
    float d0 = 0.f, d1 = 0.f, d2 = 0.f;
    for (int c = lane; c < C; c += 64) {
        float sv = s[b * C + c];
        d0 += sv * rw[c];
        d1 += sv * rw[C + c];
        d2 += sv * rw[2 * C + c];
    }
#pragma unroll
    for (int off = 32; off > 0; off >>= 1) {
        d0 += __shfl_down(d0, off);
        d1 += __shfl_down(d1, off);
        d2 += __shfl_down(d2, off);
    }
    if (lane == 0) {
        d0 += rb[0]; d1 += rb[1]; d2 += rb[2];
        if (softmax_mode) {
            float mx = fmaxf(d0, fmaxf(d1, d2));
            float e0 = expf(d0 - mx), e1 = expf(d1 - mx), e2 = expf(d2 - mx);
            float inv = 1.f / (e0 + e1 + e2);
            r[b * 3 + 0] = e0 * inv;
            r[b * 3 + 1] = e1 * inv;
            r[b * 3 + 2] = e2 * inv;
        } else {
            r[b * 3 + 0] = 1.f / (1.f + expf(-d0));
            r[b * 3 + 1] = 1.f / (1.f + expf(-d1));
            r[b * 3 + 2] = 1.f / (1.f + expf(-d2));
        }
    }
}

// ---------------------------------------------------------------------------
// Tiled GEMM: C[M,N] (+)= op(A)[M,k-range] * op(B)[k-range,N]
// 64(M) x 128(N) tile, BK=16, 4x8 microtile, synchronous body.
// blockIdx.z selects the K chunk: [z*Kchunk, min((z+1)*Kchunk, Ktot)).
// BMODE: 0 = plain B[k*N+n]
//        1 = implicit im2col from act [Ci,Bsz,H,W], scaled by r[b,e]
//        2 = implicit im2col from act [Bsz,Ci,H,W] (layer-1 input), r-scaled
// AEXPERT: A[m,kk] = dw[(e*M+m)*Kper + kq]  (experts concat along K)
// ATOMIC: epilogue atomicAdd into pre-zeroed Cout; bias added by z==0 only.
// All K bounds are guarded (handles Ktot % 16 != 0, e.g. conv1's 81).
// ---------------------------------------------------------------------------
template<int BMODE, int AEXPERT, int BIAS, int RELU, int TROUT, int ATOMIC>
__global__ __launch_bounds__(256)
void gemm_kernel(const float* __restrict__ A, const float* __restrict__ Bm,
                 const float* __restrict__ rptr, const float* __restrict__ bias,
                 float* __restrict__ Cout,
                 int M, int N, int Ktot, int Kper, int Kchunk,
                 int Ci, int Bsz, int H, int W, int lgS, int lgOW, int stride)
{
    __shared__ float As[16 * 68];    // [k][m], stride 68 (2-way max)
    __shared__ float Bs[16 * 128];   // [k][n]
    const int tid = threadIdx.x;
    const int bx = blockIdx.x, by = blockIdx.y, bz = blockIdx.z;
    const int tx = tid & 15, ty = tid >> 4;          // compute: 16x16 thread grid
    const int tk = tid & 15, tm0 = tid >> 4;         // A stage
    const int tn = tid & 127, tkb = (tid >> 7) << 3; // B stage: 8 k per thread
    const int n0 = bx << 7;
    const int ngB = n0 + tn;
    const int m0 = by << 6;
    const int kBeg = bz * Kchunk;
    const int kEnd = min(kBeg + Kchunk, Ktot);
    float acc[4][8] = {{0.f}};

    // n-side conv indices are k-independent: hoist out of the K loop
    int bB = 0, ohB = 0, owB = 0;
    float rB0 = 0.f, rB1 = 0.f, rB2 = 0.f;
    if (BMODE != 0) {
        bB = ngB >> lgS;
        int sidx = ngB & ((1 << lgS) - 1);
        ohB = sidx >> lgOW;
        owB = sidx & ((1 << lgOW) - 1);
        rB0 = rptr[bB * 3 + 0];
        rB1 = rptr[bB * 3 + 1];
        rB2 = rptr[bB * 3 + 2];
    }

    for (int k0 = kBeg; k0 < kEnd; k0 += 16) {
        // ---- stage A tile (4 m per thread, coalesced along K) ----
        {
            int kk = k0 + tk;
            int e = 0, kq = kk;
            if (AEXPERT) {
                e = (kk >= Kper) + (kk >= 2 * Kper);
                kq = kk - e * Kper;
            }
#pragma unroll
            for (int i = 0; i < 4; ++i) {
                int m = tm0 + i * 16;
                int mg = m0 + m;
                float v = 0.f;
                if (kk < kEnd && mg < M) {
                    if (AEXPERT) v = A[((size_t)(e * M + mg)) * Kper + kq];
                    else         v = A[(size_t)mg * Ktot + kk];
                }
                As[tk * 68 + m] = v;
            }
        }
        // ---- stage B tile (8 k per thread, one n) ----
#pragma unroll
        for (int j = 0; j < 8; ++j) {
            int kloc = tkb + j;
            int kk = k0 + kloc;
            float v = 0.f;
            if (kk < kEnd) {
                if (BMODE == 0) {
                    v = Bm[(size_t)kk * N + ngB];
                } else {
                    int e = (kk >= Kper) + (kk >= 2 * Kper);
                    int kq = kk - e * Kper;
                    int ci = kq / 9;
                    int rrem = kq - ci * 9;
                    int kh = rrem / 3;
                    int kw = rrem - kh * 3;
                    int ih = ohB * stride - 1 + kh;
                    int iw = owB * stride - 1 + kw;
                    if ((unsigned)ih < (unsigned)H && (unsigned)iw < (unsigned)W) {
                        size_t aidx;
                        if (BMODE == 2) aidx = (((size_t)bB * Ci + ci) * H + ih) * W + iw;
                        else            aidx = (((size_t)ci * Bsz + bB) * H + ih) * W + iw;
                        float rs = (e == 0) ? rB0 : ((e == 1) ? rB1 : rB2);
                        v = Bm[aidx] * rs;
                    }
                }
            }
            Bs[kloc * 128 + tn] = v;
        }
        __syncthreads();
        // ---- compute: 4x8 microtile, B as two float4 groups (2-way-free) ----
#pragma unroll
        for (int k = 0; k < 16; ++k) {
            float4 av  = *(const float4*)(&As[k * 68 + (ty << 2)]);
            float4 bv0 = *(const float4*)(&Bs[(k << 7) + (tx << 2)]);
            float4 bv1 = *(const float4*)(&Bs[(k << 7) + 64 + (tx << 2)]);
            float a4[4] = {av.x, av.y, av.z, av.w};
            float b8[8] = {bv0.x, bv0.y, bv0.z, bv0.w, bv1.x, bv1.y, bv1.z, bv1.w};
#pragma unroll
            for (int i = 0; i < 4; ++i)
#pragma unroll
                for (int j = 0; j < 8; ++j)
                    acc[i][j] = fmaf(a4[i], b8[j], acc[i][j]);
        }
        __syncthreads();
    }

    // ---- epilogue ----
#pragma unroll
    for (int i = 0; i < 4; ++i) {
        int mg = m0 + (ty << 2) + i;
        if (mg >= M) continue;
        float bv = (BIAS && kBeg == 0) ? bias[mg] : 0.f;
        if (ATOMIC) {
#pragma unroll
            for (int g = 0; g < 2; ++g)
#pragma unroll
                for (int j = 0; j < 4; ++j) {
                    int ng = n0 + g * 64 + (tx << 2) + j;
                    if (ng >= N) continue;
                    float v = acc[i][g * 4 + j] + bv;
                    if (TROUT) atomicAdd(&Cout[(size_t)ng * M + mg], v);
                    else       atomicAdd(&Cout[(size_t)mg * N + ng], v);
                }
        } else if (!TROUT) {
#pragma unroll
            for (int g = 0; g < 2; ++g) {
                float4 v;
                v.x = acc[i][g * 4 + 0] + bv; v.y = acc[i][g * 4 + 1] + bv;
                v.z = acc[i][g * 4 + 2] + bv; v.w = acc[i][g * 4 + 3] + bv;
                if (RELU) {
                    v.x = fmaxf(v.x, 0.f); v.y = fmaxf(v.y, 0.f);
                    v.z = fmaxf(v.z, 0.f); v.w = fmaxf(v.w, 0.f);
                }
                *(float4*)(&Cout[(size_t)mg * N + n0 + g * 64 + (tx << 2)]) = v;
            }
        } else {
#pragma unroll
            for (int g = 0; g < 2; ++g)
#pragma unroll
                for (int j = 0; j < 4; ++j) {
                    int ng = n0 + g * 64 + (tx << 2) + j;
                    if (ng >= N) continue;
                    float v = acc[i][g * 4 + j] + bv;
                    if (RELU) v = fmaxf(v, 0.f);
                    Cout[(size_t)ng * M + mg] = v;
                }
        }
    }
}

// elementwise relu in place, float4
__global__ __launch_bounds__(256)
void relu_kernel(float* __restrict__ p, int count4)
{
    int i = blockIdx.x * 256 + threadIdx.x;
    if (i >= count4) return;
    float4 v = ((const float4*)p)[i];
    v.x = fmaxf(v.x, 0.f); v.y = fmaxf(v.y, 0.f);
    v.z = fmaxf(v.z, 0.f); v.w = fmaxf(v.w, 0.f);
    ((float4*)p)[i] = v;
}

// 2x2/2 maxpool on [CB, H, W] -> [CB, H/2, W/2]
__global__ __launch_bounds__(256)
void pool_kernel(const float* __restrict__ in, float* __restrict__ out,
                 int CB, int H, int W)
{
    int OH = H >> 1, OW = W >> 1;
    int total = CB * OH * OW;
    int i = blockIdx.x * 256 + threadIdx.x;
    if (i >= total) return;
    int ow = i % OW;
    int t = i / OW;
    int oh = t % OH;
    int cb = t / OH;
    const float* p = in + ((size_t)cb * H + (oh << 1)) * W + (ow << 1);
    out[i] = fmaxf(fmaxf(p[0], p[1]), fmaxf(p[W], p[W + 1]));
}

// conv5 out [256,512,4,4] --relu+pool2x2--> hT [1024, 512] (feature-major)
__global__ __launch_bounds__(256)
void pool_flatten_kernel(const float* __restrict__ in, float* __restrict__ out)
{
    int i = blockIdx.x * 256 + threadIdx.x;     // over 256*512*4
    if (i >= 256 * 512 * 4) return;
    int b = i & 511;
    int t = i >> 9;
    int s = t & 3;          // oh*2+ow of pooled 2x2
    int c = t >> 2;
    int oh = s >> 1, ow = s & 1;
    const float* p = in + (((size_t)c * 512 + b) * 4 + (oh << 1)) * 4 + (ow << 1);
    float v = fmaxf(fmaxf(p[0], p[1]), fmaxf(p[4], p[5]));
    out[(size_t)(c * 4 + s) * 512 + b] = fmaxf(v, 0.f);
}

extern "C" void kernel_launch(void* const* d_in, const int* in_sizes, int n_in,
                              void* d_out, int out_size, void* d_ws, size_t ws_size,
                              hipStream_t stream)
{
    const float* x    = (const float*)d_in[0];
    const float* dw1  = (const float*)d_in[1];
    const float* rw1  = (const float*)d_in[2];
    const float* rb1  = (const float*)d_in[3];
    const float* dw2  = (const float*)d_in[4];
    const float* rw2  = (const float*)d_in[5];
    const float* rb2  = (const float*)d_in[6];
    const float* dw3  = (const float*)d_in[7];
    const float* rw3  = (const float*)d_in[8];
    const float* rb3  = (const float*)d_in[9];
    const float* cw4  = (const float*)d_in[10];
    const float* cr4w = (const float*)d_in[11];
    const float* cr4b = (const float*)d_in[12];
    const float* cw5  = (const float*)d_in[13];
    const float* cr5w = (const float*)d_in[14];
    const float* cr5b = (const float*)d_in[15];
    const float* fw1  = (const float*)d_in[16];
    const float* fb1  = (const float*)d_in[17];
    const float* fw2  = (const float*)d_in[18];
    const float* fb2  = (const float*)d_in[19];
    const float* fw3  = (const float*)d_in[20];
    const float* fb3  = (const float*)d_in[21];
    float* out = (float*)d_out;

    // workspace layout (floats); total ~14.9M floats = ~60 MB
    float* ws    = (float*)d_ws;
    float* r1    = ws;
    float* r2    = r1 + 1536;
    float* r3    = r2 + 1536;
    float* r4    = r3 + 1536;
    float* r5    = r4 + 1536;
    float* sdesc = ws + 8192;               // 512*384 max
    float* slabA = sdesc + 196608;          // 8,388,608 floats (c1/c2/c3/c5)
    float* slabB = slabA + 8388608;         // 2,097,152 floats (c4/fc1)
    float* a1    = slabB + 2097152;         // 2,097,152 (pooled1; later fc2 out)
    float* a2    = a1 + 2097152;            // 1,572,864 (pooled2)
    float* hT    = a2 + 1572864;            // 524,288

    const int B = 512;

    // ---- Layer 1: DyRes conv 3->64, s2 p1 -> c1 [64, 512*16*16] (direct, relu) ----
    stats_kernel<<<B * 3, 64, 0, stream>>>(x, sdesc, B, 3, 1024, 0, 1);
    routing_kernel<<<B, 64, 0, stream>>>(sdesc, rw1, rb1, r1, 3, 1);
    gemm_kernel<2, 1, 0, 1, 0, 0><<<dim3(1024, 1, 1), 256, 0, stream>>>(
        dw1, x, r1, nullptr, slabA, 64, 131072, 81, 27, 81, 3, B, 32, 32, 8, 4, 2);
    pool_kernel<<<(64 * 512 * 64) / 256, 256, 0, stream>>>(slabA, a1, 64 * 512, 16, 16);

    // ---- Layer 2: DyRes conv 64->192 -> c2 [192, 32768] (direct, relu) ----
    stats_kernel<<<B * 64, 64, 0, stream>>>(a1, sdesc, B, 64, 64, 1, 1);
    routing_kernel<<<B, 64, 0, stream>>>(sdesc, rw2, rb2, r2, 64, 1);
    gemm_kernel<1, 1, 0, 1, 0, 0><<<dim3(256, 3, 1), 256, 0, stream>>>(
        dw2, a1, r2, nullptr, slabA, 192, 32768, 1728, 576, 1728, 64, B, 8, 8, 6, 3, 1);
    pool_kernel<<<(192 * 512 * 16) / 256, 256, 0, stream>>>(slabA, a2, 192 * 512, 8, 8);

    // ---- Layer 3: DyRes conv 192->384 -> c3 [384, 8192] (split-K x3 atomic) ----
    stats_kernel<<<B * 192, 64, 0, stream>>>(a2, sdesc, B, 192, 16, 1, 1);
    routing_kernel<<<B, 64, 0, stream>>>(sdesc, rw3, rb3, r3, 192, 1);
    hipMemsetAsync(slabA, 0, (size_t)384 * 8192 * 4, stream);
    gemm_kernel<1, 1, 0, 0, 0, 1><<<dim3(64, 6, 3), 256, 0, stream>>>(
        dw3, a2, r3, nullptr, slabA, 384, 8192, 5184, 1728, 1728, 192, B, 4, 4, 4, 2, 1);
    relu_kernel<<<(384 * 8192 / 4) / 256, 256, 0, stream>>>(slabA, 384 * 8192 / 4);

    // ---- Layer 4: CondConv 384->256 -> c4 [256, 8192] (split-K x3 atomic) ----
    stats_kernel<<<B * 384, 64, 0, stream>>>(slabA, sdesc, B, 384, 16, 1, 0);
    routing_kernel<<<B, 64, 0, stream>>>(sdesc, cr4w, cr4b, r4, 384, 0);
    hipMemsetAsync(slabB, 0, (size_t)256 * 8192 * 4, stream);
    gemm_kernel<1, 1, 0, 0, 0, 1><<<dim3(64, 4, 3), 256, 0, stream>>>(
        cw4, slabA, r4, nullptr, slabB, 256, 8192, 10368, 3456, 3456, 384, B, 4, 4, 4, 2, 1);
    relu_kernel<<<(256 * 8192 / 4) / 256, 256, 0, stream>>>(slabB, 256 * 8192 / 4);

    // ---- Layer 5: CondConv 256->256 -> c5 [256, 8192] (split-K x3 atomic) ----
    stats_kernel<<<B * 256, 64, 0, stream>>>(slabB, sdesc, B, 256, 16, 1, 0);
    routing_kernel<<<B, 64, 0, stream>>>(sdesc, cr5w, cr5b, r5, 256, 0);
    hipMemsetAsync(slabA, 0, (size_t)256 * 8192 * 4, stream);
    gemm_kernel<1, 1, 0, 0, 0, 1><<<dim3(64, 4, 3), 256, 0, stream>>>(
        cw5, slabB, r5, nullptr, slabA, 256, 8192, 6912, 2304, 2304, 256, B, 4, 4, 4, 2, 1);

    // ---- relu + pool + flatten -> hT [1024, 512] ----
    pool_flatten_kernel<<<(256 * 512 * 4) / 256, 256, 0, stream>>>(slabA, hT);

    // ---- FC1: 1024 -> 4096 (split-K x4 atomic), then relu ----
    hipMemsetAsync(slabB, 0, (size_t)4096 * 512 * 4, stream);
    gemm_kernel<0, 0, 1, 0, 0, 1><<<dim3(4, 64, 4), 256, 0, stream>>>(
        fw1, hT, nullptr, fb1, slabB, 4096, 512, 1024, 0, 256, 0, 0, 0, 0, 0, 0, 0);
    relu_kernel<<<(4096 * 512 / 4) / 256, 256, 0, stream>>>(slabB, 4096 * 512 / 4);

    // ---- FC2: 4096 -> 4096 (split-K x4 atomic), then relu ----
    hipMemsetAsync(a1, 0, (size_t)4096 * 512 * 4, stream);
    gemm_kernel<0, 0, 1, 0, 0, 1><<<dim3(4, 64, 4), 256, 0, stream>>>(
        fw2, slabB, nullptr, fb2, a1, 4096, 512, 4096, 0, 1024, 0, 0, 0, 0, 0, 0, 0);
    relu_kernel<<<(4096 * 512 / 4) / 256, 256, 0, stream>>>(a1, 4096 * 512 / 4);

    // ---- FC3: 4096 -> 100 (split-K x16 atomic, transposed into d_out) ----
    hipMemsetAsync(out, 0, (size_t)512 * 100 * 4, stream);
    gemm_kernel<0, 0, 1, 0, 1, 1><<<dim3(4, 2, 16), 256, 0, stream>>>(
        fw3, a1, nullptr, fb3, out, 100, 512, 4096, 0, 256, 0, 0, 0, 0, 0, 0, 0);
}

// Round 5
// 4078.079 us; speedup vs baseline: 2.3121x; 1.0711x over previous
//
#include <hip/hip_runtime.h>
#include <math.h>

// ---------------------------------------------------------------------------
// DyRes/CondConv AlexNet forward, fp32 end-to-end.
// Every conv is an implicit-im2col GEMM with the expert mix folded into K.
// R5: deeper split-K on every heavy layer (occupancy was grid-limited at
// 4 blocks/CU on FC2) + precomputed im2col k-decode tables (kills the
// per-element div9/div3 in the gather). Body stays the proven synchronous
// 64x128 / 4x8 tile from R4 (56 VGPR, no spill).
// ---------------------------------------------------------------------------

__global__ __launch_bounds__(64)
void stats_kernel(const float* __restrict__ act, float* __restrict__ s,
                  int Bsz, int C, int HW, int cbhw, int use_std)
{
    int idx = blockIdx.x;           // b*C + c
    int b = idx / C, c = idx - b * C;
    size_t base = cbhw ? ((size_t)c * Bsz + b) : ((size_t)b * C + c);
    const float* p = act + base * HW;
    int lane = threadIdx.x;
    float sum = 0.f, sq = 0.f;
    for (int i = lane; i < HW; i += 64) { float v = p[i]; sum += v; sq += v * v; }
#pragma unroll
    for (int off = 32; off > 0; off >>= 1) {
        sum += __shfl_down(sum, off);
        sq  += __shfl_down(sq, off);
    }
    if (lane == 0) {
        float inv = 1.f / (float)HW;
        float mean = sum * inv;
        float var = sq * inv - mean * mean;
        float outv = mean;
        if (use_std) outv += sqrtf(fmaxf(var, 0.f));
        s[idx] = outv;
    }
}

// r[b,e] = softmax_e / sigmoid of (s[b,:] @ rw.T + rb), E = 3
__global__ __launch_bounds__(64)
void routing_kernel(const float* __restrict__ s, const float* __restrict__ rw,
                    const float* __restrict__ rb, float* __restrict__ r,
                    int C, int softmax_mode)
{
    int b = blockIdx.x;
    int lane = threadIdx.x;
    float d0 = 0.f, d1 = 0.f, d2 = 0.f;
    for (int c = lane; c < C; c += 64) {
        float sv = s[b * C + c];
        d0 += sv * rw[c];
        d1 += sv * rw[C + c];
        d2 += sv * rw[2 * C + c];
    }
#pragma unroll
    for (int off = 32; off > 0; off >>= 1) {
        d0 += __shfl_down(d0, off);
        d1 += __shfl_down(d1, off);
        d2 += __shfl_down(d2, off);
    }
    if (lane == 0) {
        d0 += rb[0]; d1 += rb[1]; d2 += rb[2];
        if (softmax_mode) {
            float mx = fmaxf(d0, fmaxf(d1, d2));
            float e0 = expf(d0 - mx), e1 = expf(d1 - mx), e2 = expf(d2 - mx);
            float inv = 1.f / (e0 + e1 + e2);
            r[b * 3 + 0] = e0 * inv;
            r[b * 3 + 1] = e1 * inv;
            r[b * 3 + 2] = e2 * inv;
        } else {
            r[b * 3 + 0] = 1.f / (1.f + expf(-d0));
            r[b * 3 + 1] = 1.f / (1.f + expf(-d1));
            r[b * 3 + 2] = 1.f / (1.f + expf(-d2));
        }
    }
}

// im2col k-decode table: tab[kk] = { ci*chanStride + kh*W + kw, (kh<<4)|(kw<<2)|e }
__global__ __launch_bounds__(256)
void ktab_kernel(int2* __restrict__ tab, int Ktot, int Kper, int chanStride, int W)
{
    int kk = blockIdx.x * 256 + threadIdx.x;
    if (kk >= Ktot) return;
    int e = (kk >= Kper) + (kk >= 2 * Kper);
    int kq = kk - e * Kper;
    int ci = kq / 9;
    int r9 = kq - ci * 9;
    int kh = r9 / 3;
    int kw = r9 - kh * 3;
    tab[kk] = make_int2(ci * chanStride + kh * W + kw, (kh << 4) | (kw << 2) | e);
}

// ---------------------------------------------------------------------------
// Tiled GEMM: C[M,N] (+)= op(A)[M,k-range] * op(B)[k-range,N]
// 64(M) x 128(N) tile, BK=16, 4x8 microtile, synchronous body.
// blockIdx.z selects the K chunk: [z*Kchunk, min((z+1)*Kchunk, Ktot)).
// BMODE: 0 = plain B[k*N+n]
//        1 = implicit im2col from act [Ci,Bsz,H,W] (bOff = b*H*W), r-scaled
//        2 = implicit im2col from act [Bsz,Ci,H,W] (bOff = b*Ci*H*W), r-scaled
//        (gather modes use ktab for the k-side decode)
// AEXPERT: A[m,kk] = dw[(e*M+m)*Kper + kq]  (experts concat along K)
// ATOMIC: epilogue atomicAdd into pre-zeroed Cout; bias added by z==0 only.
// ---------------------------------------------------------------------------
template<int BMODE, int AEXPERT, int BIAS, int RELU, int TROUT, int ATOMIC>
__global__ __launch_bounds__(256)
void gemm_kernel(const float* __restrict__ A, const float* __restrict__ Bm,
                 const int2* __restrict__ ktab,
                 const float* __restrict__ rptr, const float* __restrict__ bias,
                 float* __restrict__ Cout,
                 int M, int N, int Ktot, int Kper, int Kchunk,
                 int Ci, int Bsz, int H, int W, int lgS, int lgOW, int stride)
{
    __shared__ float As[16 * 68];    // [k][m], stride 68 (2-way max)
    __shared__ float Bs[16 * 128];   // [k][n]
    const int tid = threadIdx.x;
    const int bx = blockIdx.x, by = blockIdx.y, bz = blockIdx.z;
    const int tx = tid & 15, ty = tid >> 4;          // compute: 16x16 thread grid
    const int tk = tid & 15, tm0 = tid >> 4;         // A stage
    const int tn = tid & 127, tkb = (tid >> 7) << 3; // B stage: 8 k per thread
    const int n0 = bx << 7;
    const int ngB = n0 + tn;
    const int m0 = by << 6;
    const int kBeg = bz * Kchunk;
    const int kEnd = min(kBeg + Kchunk, Ktot);
    float acc[4][8] = {{0.f}};

    // n-side conv indices are k-independent: hoist out of the K loop
    int ohs = 0, ows = 0;
    float rB0 = 0.f, rB1 = 0.f, rB2 = 0.f;
    long nBase = 0;
    if (BMODE != 0) {
        int bB = ngB >> lgS;
        int sidx = ngB & ((1 << lgS) - 1);
        ohs = (sidx >> lgOW) * stride - 1;
        ows = (sidx & ((1 << lgOW) - 1)) * stride - 1;
        rB0 = rptr[bB * 3 + 0];
        rB1 = rptr[bB * 3 + 1];
        rB2 = rptr[bB * 3 + 2];
        long bOff = (BMODE == 2) ? (long)bB * Ci * H * W : (long)bB * H * W;
        nBase = bOff + (long)ohs * W + ows;
    }

    for (int k0 = kBeg; k0 < kEnd; k0 += 16) {
        // ---- stage A tile (4 m per thread, coalesced along K) ----
        {
            int kk = k0 + tk;
            int e = 0, kq = kk;
            if (AEXPERT) {
                e = (kk >= Kper) + (kk >= 2 * Kper);
                kq = kk - e * Kper;
            }
#pragma unroll
            for (int i = 0; i < 4; ++i) {
                int m = tm0 + i * 16;
                int mg = m0 + m;
                float v = 0.f;
                if (kk < kEnd && mg < M) {
                    if (AEXPERT) v = A[((size_t)(e * M + mg)) * Kper + kq];
                    else         v = A[(size_t)mg * Ktot + kk];
                }
                As[tk * 68 + m] = v;
            }
        }
        // ---- stage B tile (8 k per thread, one n) ----
#pragma unroll
        for (int j = 0; j < 8; ++j) {
            int kloc = tkb + j;
            int kk = k0 + kloc;
            float v = 0.f;
            if (kk < kEnd) {
                if (BMODE == 0) {
                    v = Bm[(size_t)kk * N + ngB];
                } else {
                    int2 t = ktab[kk];
                    int kh = t.y >> 4, kw = (t.y >> 2) & 3, e = t.y & 3;
                    int ih = ohs + kh, iw = ows + kw;
                    if ((unsigned)ih < (unsigned)H && (unsigned)iw < (unsigned)W) {
                        float rs = (e == 0) ? rB0 : ((e == 1) ? rB1 : rB2);
                        v = Bm[nBase + t.x] * rs;
                    }
                }
            }
            Bs[kloc * 128 + tn] = v;
        }
        __syncthreads();
        // ---- compute: 4x8 microtile, B as two float4 groups (2-way-free) ----
#pragma unroll
        for (int k = 0; k < 16; ++k) {
            float4 av  = *(const float4*)(&As[k * 68 + (ty << 2)]);
            float4 bv0 = *(const float4*)(&Bs[(k << 7) + (tx << 2)]);
            float4 bv1 = *(const float4*)(&Bs[(k << 7) + 64 + (tx << 2)]);
            float a4[4] = {av.x, av.y, av.z, av.w};
            float b8[8] = {bv0.x, bv0.y, bv0.z, bv0.w, bv1.x, bv1.y, bv1.z, bv1.w};
#pragma unroll
            for (int i = 0; i < 4; ++i)
#pragma unroll
                for (int j = 0; j < 8; ++j)
                    acc[i][j] = fmaf(a4[i], b8[j], acc[i][j]);
        }
        __syncthreads();
    }

    // ---- epilogue ----
#pragma unroll
    for (int i = 0; i < 4; ++i) {
        int mg = m0 + (ty << 2) + i;
        if (mg >= M) continue;
        float bv = (BIAS && kBeg == 0) ? bias[mg] : 0.f;
        if (ATOMIC) {
#pragma unroll
            for (int g = 0; g < 2; ++g)
#pragma unroll
                for (int j = 0; j < 4; ++j) {
                    int ng = n0 + g * 64 + (tx << 2) + j;
                    if (ng >= N) continue;
                    float v = acc[i][g * 4 + j] + bv;
                    if (TROUT) atomicAdd(&Cout[(size_t)ng * M + mg], v);
                    else       atomicAdd(&Cout[(size_t)mg * N + ng], v);
                }
        } else if (!TROUT) {
#pragma unroll
            for (int g = 0; g < 2; ++g) {
                float4 v;
                v.x = acc[i][g * 4 + 0] + bv; v.y = acc[i][g * 4 + 1] + bv;
                v.z = acc[i][g * 4 + 2] + bv; v.w = acc[i][g * 4 + 3] + bv;
                if (RELU) {
                    v.x = fmaxf(v.x, 0.f); v.y = fmaxf(v.y, 0.f);
                    v.z = fmaxf(v.z, 0.f); v.w = fmaxf(v.w, 0.f);
                }
                *(float4*)(&Cout[(size_t)mg * N + n0 + g * 64 + (tx << 2)]) = v;
            }
        } else {
#pragma unroll
            for (int g = 0; g < 2; ++g)
#pragma unroll
                for (int j = 0; j < 4; ++j) {
                    int ng = n0 + g * 64 + (tx << 2) + j;
                    if (ng >= N) continue;
                    float v = acc[i][g * 4 + j] + bv;
                    if (RELU) v = fmaxf(v, 0.f);
                    Cout[(size_t)ng * M + mg] = v;
                }
        }
    }
}

// elementwise relu in place, float4
__global__ __launch_bounds__(256)
void relu_kernel(float* __restrict__ p, int count4)
{
    int i = blockIdx.x * 256 + threadIdx.x;
    if (i >= count4) return;
    float4 v = ((const float4*)p)[i];
    v.x = fmaxf(v.x, 0.f); v.y = fmaxf(v.y, 0.f);
    v.z = fmaxf(v.z, 0.f); v.w = fmaxf(v.w, 0.f);
    ((float4*)p)[i] = v;
}

// 2x2/2 maxpool on [CB, H, W] -> [CB, H/2, W/2]; optional fused relu
template<int RELU>
__global__ __launch_bounds__(256)
void pool_kernel(const float* __restrict__ in, float* __restrict__ out,
                 int CB, int H, int W)
{
    int OH = H >> 1, OW = W >> 1;
    int total = CB * OH * OW;
    int i = blockIdx.x * 256 + threadIdx.x;
    if (i >= total) return;
    int ow = i % OW;
    int t = i / OW;
    int oh = t % OH;
    int cb = t / OH;
    const float* p = in + ((size_t)cb * H + (oh << 1)) * W + (ow << 1);
    float v = fmaxf(fmaxf(p[0], p[1]), fmaxf(p[W], p[W + 1]));
    if (RELU) v = fmaxf(v, 0.f);
    out[i] = v;
}

// conv5 out [256,512,4,4] --relu+pool2x2--> hT [1024, 512] (feature-major)
__global__ __launch_bounds__(256)
void pool_flatten_kernel(const float* __restrict__ in, float* __restrict__ out)
{
    int i = blockIdx.x * 256 + threadIdx.x;     // over 256*512*4
    if (i >= 256 * 512 * 4) return;
    int b = i & 511;
    int t = i >> 9;
    int s = t & 3;          // oh*2+ow of pooled 2x2
    int c = t >> 2;
    int oh = s >> 1, ow = s & 1;
    const float* p = in + (((size_t)c * 512 + b) * 4 + (oh << 1)) * 4 + (ow << 1);
    float v = fmaxf(fmaxf(p[0], p[1]), fmaxf(p[4], p[5]));
    out[(size_t)(c * 4 + s) * 512 + b] = fmaxf(v, 0.f);
}

extern "C" void kernel_launch(void* const* d_in, const int* in_sizes, int n_in,
                              void* d_out, int out_size, void* d_ws, size_t ws_size,
                              hipStream_t stream)
{
    const float* x    = (const float*)d_in[0];
    const float* dw1  = (const float*)d_in[1];
    const float* rw1  = (const float*)d_in[2];
    const float* rb1  = (const float*)d_in[3];
    const float* dw2  = (const float*)d_in[4];
    const float* rw2  = (const float*)d_in[5];
    const float* rb2  = (const float*)d_in[6];
    const float* dw3  = (const float*)d_in[7];
    const float* rw3  = (const float*)d_in[8];
    const float* rb3  = (const float*)d_in[9];
    const float* cw4  = (const float*)d_in[10];
    const float* cr4w = (const float*)d_in[11];
    const float* cr4b = (const float*)d_in[12];
    const float* cw5  = (const float*)d_in[13];
    const float* cr5w = (const float*)d_in[14];
    const float* cr5b = (const float*)d_in[15];
    const float* fw1  = (const float*)d_in[16];
    const float* fb1  = (const float*)d_in[17];
    const float* fw2  = (const float*)d_in[18];
    const float* fb2  = (const float*)d_in[19];
    const float* fw3  = (const float*)d_in[20];
    const float* fb3  = (const float*)d_in[21];
    float* out = (float*)d_out;

    // workspace layout (floats); total ~14.85M floats ~= 59.4 MB
    float* ws    = (float*)d_ws;
    float* r1    = ws;
    float* r2    = r1 + 1536;
    float* r3    = r2 + 1536;
    float* r4    = r3 + 1536;
    float* r5    = r4 + 1536;
    int2*  tabs  = (int2*)(ws + 8192);      // 32768 int2 = 65536 floats
    int2*  t1    = tabs;                    // 81
    int2*  t2    = tabs + 1024;             // 1728
    int2*  t3    = tabs + 4096;             // 5184
    int2*  t4    = tabs + 12288;            // 10368
    int2*  t5    = tabs + 24576;            // 6912
    float* sdesc = ws + 8192 + 65536;       // 512*384 max
    float* slabA = sdesc + 196608;          // 8,388,608 floats (c1/c2/c3/c5)
    float* slabB = slabA + 8388608;         // 2,097,152 floats (c4/fc1)
    float* a1    = slabB + 2097152;         // 2,097,152 (pooled1; later fc2 out)
    float* a2    = a1 + 2097152;            // 1,572,864 (pooled2)
    float* hT    = a2 + 1572864;            // 524,288

    const int B = 512;

    // ---- im2col decode tables (k -> channel/tap offset + expert) ----
    ktab_kernel<<<1, 256, 0, stream>>>(t1, 81, 27, 1024, 32);          // conv1 [B,Ci,32,32]
    ktab_kernel<<<7, 256, 0, stream>>>(t2, 1728, 576, 32768, 8);       // conv2 [Ci,B,8,8]
    ktab_kernel<<<21, 256, 0, stream>>>(t3, 5184, 1728, 8192, 4);      // conv3 [Ci,B,4,4]
    ktab_kernel<<<41, 256, 0, stream>>>(t4, 10368, 3456, 8192, 4);     // conv4
    ktab_kernel<<<27, 256, 0, stream>>>(t5, 6912, 2304, 8192, 4);      // conv5

    // ---- Layer 1: DyRes conv 3->64, s2 p1 -> c1 [64, 512*16*16] (direct, relu) ----
    stats_kernel<<<B * 3, 64, 0, stream>>>(x, sdesc, B, 3, 1024, 0, 1);
    routing_kernel<<<B, 64, 0, stream>>>(sdesc, rw1, rb1, r1, 3, 1);
    gemm_kernel<2, 1, 0, 1, 0, 0><<<dim3(1024, 1, 1), 256, 0, stream>>>(
        dw1, x, t1, r1, nullptr, slabA, 64, 131072, 81, 27, 81, 3, B, 32, 32, 8, 4, 2);
    pool_kernel<0><<<(64 * 512 * 64) / 256, 256, 0, stream>>>(slabA, a1, 64 * 512, 16, 16);

    // ---- Layer 2: DyRes conv 64->192 -> c2 [192, 32768] (split-K x3 atomic) ----
    stats_kernel<<<B * 64, 64, 0, stream>>>(a1, sdesc, B, 64, 64, 1, 1);
    routing_kernel<<<B, 64, 0, stream>>>(sdesc, rw2, rb2, r2, 64, 1);
    hipMemsetAsync(slabA, 0, (size_t)192 * 32768 * 4, stream);
    gemm_kernel<1, 1, 0, 0, 0, 1><<<dim3(256, 3, 3), 256, 0, stream>>>(
        dw2, a1, t2, r2, nullptr, slabA, 192, 32768, 1728, 576, 576, 64, B, 8, 8, 6, 3, 1);
    pool_kernel<1><<<(192 * 512 * 16) / 256, 256, 0, stream>>>(slabA, a2, 192 * 512, 8, 8);

    // ---- Layer 3: DyRes conv 192->384 -> c3 [384, 8192] (split-K x6 atomic) ----
    stats_kernel<<<B * 192, 64, 0, stream>>>(a2, sdesc, B, 192, 16, 1, 1);
    routing_kernel<<<B, 64, 0, stream>>>(sdesc, rw3, rb3, r3, 192, 1);
    hipMemsetAsync(slabA, 0, (size_t)384 * 8192 * 4, stream);
    gemm_kernel<1, 1, 0, 0, 0, 1><<<dim3(64, 6, 6), 256, 0, stream>>>(
        dw3, a2, t3, r3, nullptr, slabA, 384, 8192, 5184, 1728, 864, 192, B, 4, 4, 4, 2, 1);
    relu_kernel<<<(384 * 8192 / 4) / 256, 256, 0, stream>>>(slabA, 384 * 8192 / 4);

    // ---- Layer 4: CondConv 384->256 -> c4 [256, 8192] (split-K x6 atomic) ----
    stats_kernel<<<B * 384, 64, 0, stream>>>(slabA, sdesc, B, 384, 16, 1, 0);
    routing_kernel<<<B, 64, 0, stream>>>(sdesc, cr4w, cr4b, r4, 384, 0);
    hipMemsetAsync(slabB, 0, (size_t)256 * 8192 * 4, stream);
    gemm_kernel<1, 1, 0, 0, 0, 1><<<dim3(64, 4, 6), 256, 0, stream>>>(
        cw4, slabA, t4, r4, nullptr, slabB, 256, 8192, 10368, 3456, 1728, 384, B, 4, 4, 4, 2, 1);
    relu_kernel<<<(256 * 8192 / 4) / 256, 256, 0, stream>>>(slabB, 256 * 8192 / 4);

    // ---- Layer 5: CondConv 256->256 -> c5 [256, 8192] (split-K x6 atomic) ----
    stats_kernel<<<B * 256, 64, 0, stream>>>(slabB, sdesc, B, 256, 16, 1, 0);
    routing_kernel<<<B, 64, 0, stream>>>(sdesc, cr5w, cr5b, r5, 256, 0);
    hipMemsetAsync(slabA, 0, (size_t)256 * 8192 * 4, stream);
    gemm_kernel<1, 1, 0, 0, 0, 1><<<dim3(64, 4, 6), 256, 0, stream>>>(
        cw5, slabB, t5, r5, nullptr, slabA, 256, 8192, 6912, 2304, 1152, 256, B, 4, 4, 4, 2, 1);

    // ---- relu + pool + flatten -> hT [1024, 512] ----
    pool_flatten_kernel<<<(256 * 512 * 4) / 256, 256, 0, stream>>>(slabA, hT);

    // ---- FC1: 1024 -> 4096 (split-K x8 atomic), then relu ----
    hipMemsetAsync(slabB, 0, (size_t)4096 * 512 * 4, stream);
    gemm_kernel<0, 0, 1, 0, 0, 1><<<dim3(4, 64, 8), 256, 0, stream>>>(
        fw1, hT, nullptr, nullptr, fb1, slabB, 4096, 512, 1024, 0, 128, 0, 0, 0, 0, 0, 0, 0);
    relu_kernel<<<(4096 * 512 / 4) / 256, 256, 0, stream>>>(slabB, 4096 * 512 / 4);

    // ---- FC2: 4096 -> 4096 (split-K x8 atomic), then relu ----
    hipMemsetAsync(a1, 0, (size_t)4096 * 512 * 4, stream);
    gemm_kernel<0, 0, 1, 0, 0, 1><<<dim3(4, 64, 8), 256, 0, stream>>>(
        fw2, slabB, nullptr, nullptr, fb2, a1, 4096, 512, 4096, 0, 512, 0, 0, 0, 0, 0, 0, 0);
    relu_kernel<<<(4096 * 512 / 4) / 256, 256, 0, stream>>>(a1, 4096 * 512 / 4);

    // ---- FC3: 4096 -> 100 (split-K x32 atomic, transposed into d_out) ----
    hipMemsetAsync(out, 0, (size_t)512 * 100 * 4, stream);
    gemm_kernel<0, 0, 1, 0, 1, 1><<<dim3(4, 2, 32), 256, 0, stream>>>(
        fw3, a1, nullptr, nullptr, fb3, out, 100, 512, 4096, 0, 128, 0, 0, 0, 0, 0, 0, 0);
}

// Round 6
// 2981.238 us; speedup vs baseline: 3.1628x; 1.3679x over previous
//
#include <hip/hip_runtime.h>
#include <math.h>

// ---------------------------------------------------------------------------
// DyRes/CondConv AlexNet forward. R6: all GEMMs moved to MFMA with
// double-bf16 decomposition (a = ah + al; ah*bh + ah*bl + al*bh, fp32 acc).
// Activations pre-packed as (hi16<<16)|lo16 uint32; expert scale r[b,e]
// applied in the epilogue (split-K chunks aligned to expert boundaries).
// Tile 64Mx128Nx32K, 4 waves, split-K fp32 atomics.
// ---------------------------------------------------------------------------

typedef unsigned short u16;
typedef unsigned int u32;
typedef short bf16x8 __attribute__((ext_vector_type(8)));
typedef float f32x4 __attribute__((ext_vector_type(4)));

__device__ __forceinline__ u16 bf16_rne(float f) {
    u32 u = __float_as_uint(f);
    return (u16)((u + 0x7fffu + ((u >> 16) & 1u)) >> 16);
}
__device__ __forceinline__ u32 packsplit(float v) {
    u16 h = bf16_rne(v);
    float hf = __uint_as_float((u32)h << 16);
    u16 l = bf16_rne(v - hf);
    return ((u32)h << 16) | l;
}
__device__ __forceinline__ float unpackf(u32 p) {
    return __uint_as_float(p & 0xffff0000u) + __uint_as_float(p << 16);
}

__global__ __launch_bounds__(64)
void stats_kernel(const void* __restrict__ actv, float* __restrict__ s,
                  int Bsz, int C, int HW, int cbhw, int use_std, int packed)
{
    int idx = blockIdx.x;           // b*C + c
    int b = idx / C, c = idx - b * C;
    size_t base = (cbhw ? ((size_t)c * Bsz + b) : ((size_t)b * C + c)) * HW;
    int lane = threadIdx.x;
    float sum = 0.f, sq = 0.f;
    if (packed) {
        const u32* p = (const u32*)actv + base;
        for (int i = lane; i < HW; i += 64) { float v = unpackf(p[i]); sum += v; sq += v * v; }
    } else {
        const float* p = (const float*)actv + base;
        for (int i = lane; i < HW; i += 64) { float v = p[i]; sum += v; sq += v * v; }
    }
#pragma unroll
    for (int off = 32; off > 0; off >>= 1) {
        sum += __shfl_down(sum, off);
        sq  += __shfl_down(sq, off);
    }
    if (lane == 0) {
        float inv = 1.f / (float)HW;
        float mean = sum * inv;
        float var = sq * inv - mean * mean;
        float outv = mean;
        if (use_std) outv += sqrtf(fmaxf(var, 0.f));
        s[idx] = outv;
    }
}

__global__ __launch_bounds__(64)
void routing_kernel(const float* __restrict__ s, const float* __restrict__ rw,
                    const float* __restrict__ rb, float* __restrict__ r,
                    int C, int softmax_mode)
{
    int b = blockIdx.x;
    int lane = threadIdx.x;
    float d0 = 0.f, d1 = 0.f, d2 = 0.f;
    for (int c = lane; c < C; c += 64) {
        float sv = s[b * C + c];
        d0 += sv * rw[c];
        d1 += sv * rw[C + c];
        d2 += sv * rw[2 * C + c];
    }
#pragma unroll
    for (int off = 32; off > 0; off >>= 1) {
        d0 += __shfl_down(d0, off);
        d1 += __shfl_down(d1, off);
        d2 += __shfl_down(d2, off);
    }
    if (lane == 0) {
        d0 += rb[0]; d1 += rb[1]; d2 += rb[2];
        if (softmax_mode) {
            float mx = fmaxf(d0, fmaxf(d1, d2));
            float e0 = expf(d0 - mx), e1 = expf(d1 - mx), e2 = expf(d2 - mx);
            float inv = 1.f / (e0 + e1 + e2);
            r[b * 3 + 0] = e0 * inv;
            r[b * 3 + 1] = e1 * inv;
            r[b * 3 + 2] = e2 * inv;
        } else {
            r[b * 3 + 0] = 1.f / (1.f + expf(-d0));
            r[b * 3 + 1] = 1.f / (1.f + expf(-d1));
            r[b * 3 + 2] = 1.f / (1.f + expf(-d2));
        }
    }
}

// im2col k-decode table: tab[kk] = { ci*chanStride + kh*W + kw, (kh<<4)|(kw<<2)|e }
__global__ __launch_bounds__(256)
void ktab_kernel(int2* __restrict__ tab, int Ktot, int Kper, int chanStride, int W)
{
    int kk = blockIdx.x * 256 + threadIdx.x;
    if (kk >= Ktot) return;
    int e = (kk >= Kper) + (kk >= 2 * Kper);
    int kq = kk - e * Kper;
    int ci = kq / 9;
    int r9 = kq - ci * 9;
    int kh = r9 / 3;
    int kw = r9 - kh * 3;
    tab[kk] = make_int2(ci * chanStride + kh * W + kw, (kh << 4) | (kw << 2) | e);
}

// ---------------------------------------------------------------------------
// MFMA GEMM: C[M,N] (+)= A[M,krange] * B[krange,N], split-bf16 x3 products.
// Tile 64(M) x 128(N), BK=32. 4 waves: wave w owns n-slice [w*32, w*32+32).
// BMODE 0: B = packed activation, layout [n][Ktot] (pre-transposed).
// BMODE 1: gather packed act [Ci,Bsz,H,W]; BMODE 2: gather [Bsz,Ci,H,W].
// AEXPERT: A[m,kk] = W[(e*M+m)*Kper + kq], e = bz/zpe (chunks expert-aligned);
//          epilogue multiplies by r[b(n),e].
// Epilogue: fp32 atomicAdd into pre-zeroed Cout; bias added by bz==0 only.
// ---------------------------------------------------------------------------
template<int BMODE, int AEXPERT, int BIAS, int TROUT>
__global__ __launch_bounds__(256)
void mgemm_kernel(const float* __restrict__ A, const u32* __restrict__ Bpk,
                  const int2* __restrict__ ktab,
                  const float* __restrict__ rptr, const float* __restrict__ bias,
                  float* __restrict__ Cout,
                  int M, int N, int Ktot, int Kper, int Kchunk, int zpe,
                  int Ci, int Bsz, int H, int W, int lgS, int lgOW, int stride)
{
    __shared__ u16 Ah[64 * 40], Al[64 * 40];     // row m, stride 40 u16 (80 B)
    __shared__ u16 Bh[128 * 40], Bl[128 * 40];   // row n
    const int tid = threadIdx.x;
    const int n0 = blockIdx.x << 7, m0 = blockIdx.y << 6;
    const int bz = blockIdx.z;
    const int kBeg = bz * Kchunk;
    const int kEnd = min(kBeg + Kchunk, Ktot);
    const int eA = AEXPERT ? (bz / zpe) : 0;

    const int tmA = tid >> 2, tkA = (tid & 3) << 3;    // A: 64 m x (4x8) k
    const int tnB = tid & 127, tkB = (tid >> 7) << 4;  // B: 128 n x (2x16) k

    int ohs = 0, ows = 0; long nBase = 0;
    if (BMODE != 0) {
        int nn = n0 + tnB;
        int bB = nn >> lgS;
        int sidx = nn & ((1 << lgS) - 1);
        ohs = (sidx >> lgOW) * stride - 1;
        ows = (sidx & ((1 << lgOW) - 1)) * stride - 1;
        long bOff = (BMODE == 2) ? (long)bB * Ci * H * W : (long)bB * H * W;
        nBase = bOff + (long)ohs * W + ows;
    }

    const int lane = tid & 63, wv = tid >> 6;
    const int lm = lane & 15, qd = lane >> 4;

    f32x4 acc[4][2];
#pragma unroll
    for (int i = 0; i < 4; ++i)
#pragma unroll
        for (int j = 0; j < 2; ++j)
            acc[i][j] = (f32x4){0.f, 0.f, 0.f, 0.f};

    for (int k0 = kBeg; k0 < kEnd; k0 += 32) {
        // ---- stage A (weights, split in-kernel) ----
        {
            u16 hs[8], ls[8];
            int mg = m0 + tmA;
            bool mok = mg < M;
#pragma unroll
            for (int j = 0; j < 8; ++j) {
                int kk = k0 + tkA + j;
                float a = 0.f;
                if (mok && kk < kEnd)
                    a = AEXPERT ? A[(size_t)(eA * M + mg) * Kper + (kk - eA * Kper)]
                                : A[(size_t)mg * Ktot + kk];
                u16 h = bf16_rne(a);
                hs[j] = h;
                ls[j] = bf16_rne(a - __uint_as_float((u32)h << 16));
            }
            uint4 hv, lv;
            hv.x = hs[0] | ((u32)hs[1] << 16); hv.y = hs[2] | ((u32)hs[3] << 16);
            hv.z = hs[4] | ((u32)hs[5] << 16); hv.w = hs[6] | ((u32)hs[7] << 16);
            lv.x = ls[0] | ((u32)ls[1] << 16); lv.y = ls[2] | ((u32)ls[3] << 16);
            lv.z = ls[4] | ((u32)ls[5] << 16); lv.w = ls[6] | ((u32)ls[7] << 16);
            *(uint4*)(&Ah[tmA * 40 + tkA]) = hv;
            *(uint4*)(&Al[tmA * 40 + tkA]) = lv;
        }
        // ---- stage B (pre-packed activations) ----
        {
            u16 hs[16], ls[16];
            if (BMODE == 0) {
                const u32* bp = Bpk + (size_t)(n0 + tnB) * Ktot + k0 + tkB;
#pragma unroll
                for (int j = 0; j < 16; j += 4) {
                    uint4 q = *(const uint4*)(bp + j);
                    hs[j+0] = q.x >> 16; ls[j+0] = q.x & 0xffffu;
                    hs[j+1] = q.y >> 16; ls[j+1] = q.y & 0xffffu;
                    hs[j+2] = q.z >> 16; ls[j+2] = q.z & 0xffffu;
                    hs[j+3] = q.w >> 16; ls[j+3] = q.w & 0xffffu;
                }
            } else {
#pragma unroll
                for (int j = 0; j < 16; ++j) {
                    int kk = k0 + tkB + j;
                    u32 p = 0;
                    if (kk < kEnd) {
                        int2 t = ktab[kk];
                        int ih = ohs + (t.y >> 4), iw = ows + ((t.y >> 2) & 3);
                        if ((unsigned)ih < (unsigned)H && (unsigned)iw < (unsigned)W)
                            p = Bpk[nBase + t.x];
                    }
                    hs[j] = p >> 16; ls[j] = p & 0xffffu;
                }
            }
            uint4 h0, h1, l0, l1;
            h0.x = hs[0] | ((u32)hs[1] << 16);  h0.y = hs[2] | ((u32)hs[3] << 16);
            h0.z = hs[4] | ((u32)hs[5] << 16);  h0.w = hs[6] | ((u32)hs[7] << 16);
            h1.x = hs[8] | ((u32)hs[9] << 16);  h1.y = hs[10] | ((u32)hs[11] << 16);
            h1.z = hs[12] | ((u32)hs[13] << 16); h1.w = hs[14] | ((u32)hs[15] << 16);
            l0.x = ls[0] | ((u32)ls[1] << 16);  l0.y = ls[2] | ((u32)ls[3] << 16);
            l0.z = ls[4] | ((u32)ls[5] << 16);  l0.w = ls[6] | ((u32)ls[7] << 16);
            l1.x = ls[8] | ((u32)ls[9] << 16);  l1.y = ls[10] | ((u32)ls[11] << 16);
            l1.z = ls[12] | ((u32)ls[13] << 16); l1.w = ls[14] | ((u32)ls[15] << 16);
            *(uint4*)(&Bh[tnB * 40 + tkB])     = h0;
            *(uint4*)(&Bh[tnB * 40 + tkB + 8]) = h1;
            *(uint4*)(&Bl[tnB * 40 + tkB])     = l0;
            *(uint4*)(&Bl[tnB * 40 + tkB + 8]) = l1;
        }
        __syncthreads();
        // ---- fragments + MFMA (3 products: al*bh, ah*bl, ah*bh) ----
        {
            bf16x8 ah[4], al[4], bh[2], bl[2];
#pragma unroll
            for (int mi = 0; mi < 4; ++mi) {
                int row = mi * 16 + lm;
                ah[mi] = *(const bf16x8*)(&Ah[row * 40 + qd * 8]);
                al[mi] = *(const bf16x8*)(&Al[row * 40 + qd * 8]);
            }
#pragma unroll
            for (int ni = 0; ni < 2; ++ni) {
                int row = wv * 32 + ni * 16 + lm;
                bh[ni] = *(const bf16x8*)(&Bh[row * 40 + qd * 8]);
                bl[ni] = *(const bf16x8*)(&Bl[row * 40 + qd * 8]);
            }
#pragma unroll
            for (int mi = 0; mi < 4; ++mi)
#pragma unroll
                for (int ni = 0; ni < 2; ++ni) {
                    f32x4 c = acc[mi][ni];
                    c = __builtin_amdgcn_mfma_f32_16x16x32_bf16(al[mi], bh[ni], c, 0, 0, 0);
                    c = __builtin_amdgcn_mfma_f32_16x16x32_bf16(ah[mi], bl[ni], c, 0, 0, 0);
                    c = __builtin_amdgcn_mfma_f32_16x16x32_bf16(ah[mi], bh[ni], c, 0, 0, 0);
                    acc[mi][ni] = c;
                }
        }
        __syncthreads();
    }

    // ---- epilogue: scale by r[b,e] (convs), bias (z0), fp32 atomicAdd ----
#pragma unroll
    for (int ni = 0; ni < 2; ++ni) {
        int n = n0 + wv * 32 + ni * 16 + lm;
        if (n >= N) continue;
        float rs = 1.f;
        if (BMODE != 0) rs = rptr[(n >> lgS) * 3 + eA];
#pragma unroll
        for (int mi = 0; mi < 4; ++mi)
#pragma unroll
            for (int r = 0; r < 4; ++r) {
                int m = m0 + mi * 16 + qd * 4 + r;
                if (m >= M) continue;
                float v = acc[mi][ni][r];
                if (BMODE != 0) v *= rs;
                if (BIAS && bz == 0) v += bias[m];
                if (TROUT) atomicAdd(&Cout[(size_t)n * M + m], v);
                else       atomicAdd(&Cout[(size_t)m * N + n], v);
            }
    }
}

// elementwise fp32 -> packed bf16x2 (optional relu)
__global__ __launch_bounds__(256)
void pack_kernel(const float* __restrict__ in, u32* __restrict__ outp,
                 int count, int relu)
{
    int i = blockIdx.x * 256 + threadIdx.x;
    if (i >= count) return;
    float v = in[i];
    if (relu) v = fmaxf(v, 0.f);
    outp[i] = packsplit(v);
}

// 2x2/2 maxpool + relu, fp32 in -> packed out
template<int RELU>
__global__ __launch_bounds__(256)
void pool_pack_kernel(const float* __restrict__ in, u32* __restrict__ outp,
                      int CB, int H, int W)
{
    int OH = H >> 1, OW = W >> 1;
    int total = CB * OH * OW;
    int i = blockIdx.x * 256 + threadIdx.x;
    if (i >= total) return;
    int ow = i % OW;
    int t = i / OW;
    int oh = t % OH;
    int cb = t / OH;
    const float* p = in + ((size_t)cb * H + (oh << 1)) * W + (ow << 1);
    float v = fmaxf(fmaxf(p[0], p[1]), fmaxf(p[W], p[W + 1]));
    if (RELU) v = fmaxf(v, 0.f);
    outp[i] = packsplit(v);
}

// conv5 fp32 [256,512,4,4] --relu+pool--> packed hT [b][1024] (n-major for FC)
__global__ __launch_bounds__(256)
void pool_flatten_pack_kernel(const float* __restrict__ in, u32* __restrict__ outp)
{
    int i = blockIdx.x * 256 + threadIdx.x;     // over 512*1024, b-major
    if (i >= 512 * 1024) return;
    int b = i >> 10;
    int f = i & 1023;
    int c = f >> 2, s = f & 3;
    int oh = s >> 1, ow = s & 1;
    const float* p = in + (((size_t)c * 512 + b) * 4 + (oh << 1)) * 4 + (ow << 1);
    float v = fmaxf(fmaxf(p[0], p[1]), fmaxf(p[4], p[5]));
    outp[i] = packsplit(fmaxf(v, 0.f));
}

// FC act: fp32 [Mt][Nt] --relu--> packed transposed [Nt][Mt] (LDS-tiled)
__global__ __launch_bounds__(256)
void tp_pack_kernel(const float* __restrict__ in, u32* __restrict__ outp,
                    int Mt, int Nt)
{
    __shared__ float t[32][33];
    int tx = threadIdx.x & 31, ty = threadIdx.x >> 5;   // ty 0..7
    int mB = blockIdx.x << 5, nB = blockIdx.y << 5;
#pragma unroll
    for (int i = 0; i < 4; ++i) {
        int mm = ty + i * 8;
        t[mm][tx] = in[(size_t)(mB + mm) * Nt + nB + tx];
    }
    __syncthreads();
#pragma unroll
    for (int i = 0; i < 4; ++i) {
        int nn = ty + i * 8;
        float v = fmaxf(t[tx][nn], 0.f);
        outp[(size_t)(nB + nn) * Mt + mB + tx] = packsplit(v);
    }
}

extern "C" void kernel_launch(void* const* d_in, const int* in_sizes, int n_in,
                              void* d_out, int out_size, void* d_ws, size_t ws_size,
                              hipStream_t stream)
{
    const float* x    = (const float*)d_in[0];
    const float* dw1  = (const float*)d_in[1];
    const float* rw1  = (const float*)d_in[2];
    const float* rb1  = (const float*)d_in[3];
    const float* dw2  = (const float*)d_in[4];
    const float* rw2  = (const float*)d_in[5];
    const float* rb2  = (const float*)d_in[6];
    const float* dw3  = (const float*)d_in[7];
    const float* rw3  = (const float*)d_in[8];
    const float* rb3  = (const float*)d_in[9];
    const float* cw4  = (const float*)d_in[10];
    const float* cr4w = (const float*)d_in[11];
    const float* cr4b = (const float*)d_in[12];
    const float* cw5  = (const float*)d_in[13];
    const float* cr5w = (const float*)d_in[14];
    const float* cr5b = (const float*)d_in[15];
    const float* fw1  = (const float*)d_in[16];
    const float* fb1  = (const float*)d_in[17];
    const float* fw2  = (const float*)d_in[18];
    const float* fb2  = (const float*)d_in[19];
    const float* fw3  = (const float*)d_in[20];
    const float* fb3  = (const float*)d_in[21];
    float* out = (float*)d_out;

    // workspace layout (float units); total ~15.0M floats ~= 60 MB
    float* ws    = (float*)d_ws;
    float* r1    = ws;                      // 5 x 1536 routing
    float* r2    = r1 + 1536;
    float* r3    = r2 + 1536;
    float* r4    = r3 + 1536;
    float* r5    = r4 + 1536;
    int2*  tabs  = (int2*)(ws + 8192);      // 32768 int2
    int2*  t1    = tabs;
    int2*  t2    = tabs + 1024;
    int2*  t3    = tabs + 4096;
    int2*  t4    = tabs + 12288;
    int2*  t5    = tabs + 24576;
    float* sdesc = ws + 8192 + 65536;       // 196608
    float* slab  = sdesc + 196608;          // 8,388,608 fp32 (all conv/fc outs)
    u32*   P1    = (u32*)(slab + 8388608);  // 3,145,728 u32
    u32*   P2    = P1 + 3145728;            // 3,145,728 u32

    // packed-activation buffer assignments (lifetimes alternate P1/P2)
    u32* xpk   = P1;   // 1.57M
    u32* a1pk  = P2;   // 2.10M
    u32* a2pk  = P1;   // 1.57M
    u32* c3pk  = P2;   // 3.15M
    u32* c4pk  = P1;   // 2.10M
    u32* hTpk  = P2;   // 0.52M
    u32* f1pkT = P1;   // 2.10M
    u32* f2pkT = P2;   // 2.10M

    const int B = 512;

    // ---- decode tables + input pack ----
    ktab_kernel<<<1, 256, 0, stream>>>(t1, 81, 27, 1024, 32);
    ktab_kernel<<<7, 256, 0, stream>>>(t2, 1728, 576, 32768, 8);
    ktab_kernel<<<21, 256, 0, stream>>>(t3, 5184, 1728, 8192, 4);
    ktab_kernel<<<41, 256, 0, stream>>>(t4, 10368, 3456, 8192, 4);
    ktab_kernel<<<27, 256, 0, stream>>>(t5, 6912, 2304, 8192, 4);
    pack_kernel<<<6144, 256, 0, stream>>>(x, xpk, 1572864, 0);

    // ---- Layer 1: DyRes conv 3->64, s2 p1 -> slab [64, 131072] ----
    stats_kernel<<<B * 3, 64, 0, stream>>>(x, sdesc, B, 3, 1024, 0, 1, 0);
    routing_kernel<<<B, 64, 0, stream>>>(sdesc, rw1, rb1, r1, 3, 1);
    hipMemsetAsync(slab, 0, (size_t)64 * 131072 * 4, stream);
    mgemm_kernel<2, 1, 0, 0><<<dim3(1024, 1, 3), 256, 0, stream>>>(
        dw1, xpk, t1, r1, nullptr, slab, 64, 131072, 81, 27, 27, 1, 3, B, 32, 32, 8, 4, 2);
    pool_pack_kernel<1><<<8192, 256, 0, stream>>>(slab, a1pk, 64 * 512, 16, 16);

    // ---- Layer 2: DyRes conv 64->192 -> slab [192, 32768] ----
    stats_kernel<<<B * 64, 64, 0, stream>>>(a1pk, sdesc, B, 64, 64, 1, 1, 1);
    routing_kernel<<<B, 64, 0, stream>>>(sdesc, rw2, rb2, r2, 64, 1);
    hipMemsetAsync(slab, 0, (size_t)192 * 32768 * 4, stream);
    mgemm_kernel<1, 1, 0, 0><<<dim3(256, 3, 3), 256, 0, stream>>>(
        dw2, a1pk, t2, r2, nullptr, slab, 192, 32768, 1728, 576, 576, 1, 64, B, 8, 8, 6, 3, 1);
    pool_pack_kernel<1><<<6144, 256, 0, stream>>>(slab, a2pk, 192 * 512, 8, 8);

    // ---- Layer 3: DyRes conv 192->384 -> slab [384, 8192] ----
    stats_kernel<<<B * 192, 64, 0, stream>>>(a2pk, sdesc, B, 192, 16, 1, 1, 1);
    routing_kernel<<<B, 64, 0, stream>>>(sdesc, rw3, rb3, r3, 192, 1);
    hipMemsetAsync(slab, 0, (size_t)384 * 8192 * 4, stream);
    mgemm_kernel<1, 1, 0, 0><<<dim3(64, 6, 6), 256, 0, stream>>>(
        dw3, a2pk, t3, r3, nullptr, slab, 384, 8192, 5184, 1728, 864, 2, 192, B, 4, 4, 4, 2, 1);
    pack_kernel<<<12288, 256, 0, stream>>>(slab, c3pk, 3145728, 1);

    // ---- Layer 4: CondConv 384->256 -> slab [256, 8192] ----
    stats_kernel<<<B * 384, 64, 0, stream>>>(c3pk, sdesc, B, 384, 16, 1, 0, 1);
    routing_kernel<<<B, 64, 0, stream>>>(sdesc, cr4w, cr4b, r4, 384, 0);
    hipMemsetAsync(slab, 0, (size_t)256 * 8192 * 4, stream);
    mgemm_kernel<1, 1, 0, 0><<<dim3(64, 4, 6), 256, 0, stream>>>(
        cw4, c3pk, t4, r4, nullptr, slab, 256, 8192, 10368, 3456, 1728, 2, 384, B, 4, 4, 4, 2, 1);
    pack_kernel<<<8192, 256, 0, stream>>>(slab, c4pk, 2097152, 1);

    // ---- Layer 5: CondConv 256->256 -> slab [256, 8192] ----
    stats_kernel<<<B * 256, 64, 0, stream>>>(c4pk, sdesc, B, 256, 16, 1, 0, 1);
    routing_kernel<<<B, 64, 0, stream>>>(sdesc, cr5w, cr5b, r5, 256, 0);
    hipMemsetAsync(slab, 0, (size_t)256 * 8192 * 4, stream);
    mgemm_kernel<1, 1, 0, 0><<<dim3(64, 4, 6), 256, 0, stream>>>(
        cw5, c4pk, t5, r5, nullptr, slab, 256, 8192, 6912, 2304, 1152, 2, 256, B, 4, 4, 4, 2, 1);

    // ---- relu + pool + flatten -> packed hT [512][1024] ----
    pool_flatten_pack_kernel<<<2048, 256, 0, stream>>>(slab, hTpk);

    // ---- FC1: 1024 -> 4096 -> slab [4096, 512]; relu+transpose-pack ----
    hipMemsetAsync(slab, 0, (size_t)4096 * 512 * 4, stream);
    mgemm_kernel<0, 0, 1, 0><<<dim3(4, 64, 4), 256, 0, stream>>>(
        fw1, hTpk, nullptr, nullptr, fb1, slab, 4096, 512, 1024, 0, 256, 1, 0, 0, 0, 0, 0, 0, 0);
    tp_pack_kernel<<<dim3(128, 16), 256, 0, stream>>>(slab, f1pkT, 4096, 512);

    // ---- FC2: 4096 -> 4096 -> slab; relu+transpose-pack ----
    hipMemsetAsync(slab, 0, (size_t)4096 * 512 * 4, stream);
    mgemm_kernel<0, 0, 1, 0><<<dim3(4, 64, 8), 256, 0, stream>>>(
        fw2, f1pkT, nullptr, nullptr, fb2, slab, 4096, 512, 4096, 0, 512, 1, 0, 0, 0, 0, 0, 0, 0);
    tp_pack_kernel<<<dim3(128, 16), 256, 0, stream>>>(slab, f2pkT, 4096, 512);

    // ---- FC3: 4096 -> 100, transposed store into d_out [512, 100] ----
    hipMemsetAsync(out, 0, (size_t)512 * 100 * 4, stream);
    mgemm_kernel<0, 0, 1, 1><<<dim3(4, 2, 8), 256, 0, stream>>>(
        fw3, f2pkT, nullptr, nullptr, fb3, out, 100, 512, 4096, 0, 512, 1, 0, 0, 0, 0, 0, 0, 0);
}

// Round 7
// 1881.657 us; speedup vs baseline: 5.0110x; 1.5844x over previous
//
#include <hip/hip_runtime.h>
#include <math.h>

// ---------------------------------------------------------------------------
// DyRes/CondConv AlexNet forward. R7: MFMA double-bf16 (3 products) kept from
// R6; staging VALU removed from the hot loop: weights pre-split per layer into
// K-padded bf16 hi/lo planes (pure b128 copies in-kernel), B stays packed u32
// in LDS (gather -> b128 store, zero repack; unpack at fragment read).
// Tile 128Mx128N (4 waves, 64x64 each), BK=32, split-K fp32 atomics.
// Weight-plane scratch overlaps the tail of the fp32 out-slab region.
// ---------------------------------------------------------------------------

typedef unsigned short u16;
typedef unsigned int u32;
typedef short bf16x8 __attribute__((ext_vector_type(8)));
typedef float f32x4 __attribute__((ext_vector_type(4)));

__device__ __forceinline__ u16 bf16_rne(float f) {
    u32 u = __float_as_uint(f);
    return (u16)((u + 0x7fffu + ((u >> 16) & 1u)) >> 16);
}
__device__ __forceinline__ u32 packsplit(float v) {
    u16 h = bf16_rne(v);
    float hf = __uint_as_float((u32)h << 16);
    u16 l = bf16_rne(v - hf);
    return ((u32)h << 16) | l;
}
__device__ __forceinline__ float unpackf(u32 p) {
    return __uint_as_float(p & 0xffff0000u) + __uint_as_float(p << 16);
}

// fp32 weights -> K-padded bf16 hi/lo planes (zero-padded beyond Kper)
__global__ __launch_bounds__(256)
void wsplit_kernel(const float* __restrict__ W, u16* __restrict__ whi,
                   u16* __restrict__ wlo, int total, int Kper, int Kpad)
{
    int idx = blockIdx.x * 256 + threadIdx.x;
    if (idx >= total) return;
    int r = idx / Kpad, k = idx - r * Kpad;
    float v = (k < Kper) ? W[(size_t)r * Kper + k] : 0.f;
    u16 h = bf16_rne(v);
    whi[idx] = h;
    wlo[idx] = bf16_rne(v - __uint_as_float((u32)h << 16));
}

__global__ __launch_bounds__(64)
void stats_kernel(const void* __restrict__ actv, float* __restrict__ s,
                  int Bsz, int C, int HW, int cbhw, int use_std, int packed)
{
    int idx = blockIdx.x;           // b*C + c
    int b = idx / C, c = idx - b * C;
    size_t base = (cbhw ? ((size_t)c * Bsz + b) : ((size_t)b * C + c)) * HW;
    int lane = threadIdx.x;
    float sum = 0.f, sq = 0.f;
    if (packed) {
        const u32* p = (const u32*)actv + base;
        for (int i = lane; i < HW; i += 64) { float v = unpackf(p[i]); sum += v; sq += v * v; }
    } else {
        const float* p = (const float*)actv + base;
        for (int i = lane; i < HW; i += 64) { float v = p[i]; sum += v; sq += v * v; }
    }
#pragma unroll
    for (int off = 32; off > 0; off >>= 1) {
        sum += __shfl_down(sum, off);
        sq  += __shfl_down(sq, off);
    }
    if (lane == 0) {
        float inv = 1.f / (float)HW;
        float mean = sum * inv;
        float var = sq * inv - mean * mean;
        float outv = mean;
        if (use_std) outv += sqrtf(fmaxf(var, 0.f));
        s[idx] = outv;
    }
}

__global__ __launch_bounds__(64)
void routing_kernel(const float* __restrict__ s, const float* __restrict__ rw,
                    const float* __restrict__ rb, float* __restrict__ r,
                    int C, int softmax_mode)
{
    int b = blockIdx.x;
    int lane = threadIdx.x;
    float d0 = 0.f, d1 = 0.f, d2 = 0.f;
    for (int c = lane; c < C; c += 64) {
        float sv = s[b * C + c];
        d0 += sv * rw[c];
        d1 += sv * rw[C + c];
        d2 += sv * rw[2 * C + c];
    }
#pragma unroll
    for (int off = 32; off > 0; off >>= 1) {
        d0 += __shfl_down(d0, off);
        d1 += __shfl_down(d1, off);
        d2 += __shfl_down(d2, off);
    }
    if (lane == 0) {
        d0 += rb[0]; d1 += rb[1]; d2 += rb[2];
        if (softmax_mode) {
            float mx = fmaxf(d0, fmaxf(d1, d2));
            float e0 = expf(d0 - mx), e1 = expf(d1 - mx), e2 = expf(d2 - mx);
            float inv = 1.f / (e0 + e1 + e2);
            r[b * 3 + 0] = e0 * inv;
            r[b * 3 + 1] = e1 * inv;
            r[b * 3 + 2] = e2 * inv;
        } else {
            r[b * 3 + 0] = 1.f / (1.f + expf(-d0));
            r[b * 3 + 1] = 1.f / (1.f + expf(-d1));
            r[b * 3 + 2] = 1.f / (1.f + expf(-d2));
        }
    }
}

// padded im2col k-decode: kk in [0, 3*Kpad); pad entries get OOB sentinel kh=15
__global__ __launch_bounds__(256)
void ktab_kernel(int2* __restrict__ tab, int Kpad, int Kper, int chanStride, int W)
{
    int kk = blockIdx.x * 256 + threadIdx.x;
    if (kk >= 3 * Kpad) return;
    int e = kk / Kpad;
    int kq = kk - e * Kpad;
    if (kq >= Kper) { tab[kk] = make_int2(0, 15 << 4); return; }
    int ci = kq / 9;
    int r9 = kq - ci * 9;
    int kh = r9 / 3;
    int kw = r9 - kh * 3;
    tab[kk] = make_int2(ci * chanStride + kh * W + kw, (kh << 4) | (kw << 2));
}

// ---------------------------------------------------------------------------
// MFMA GEMM, 128Mx128N tile, BK=32, 4 waves (2x2), wave tile 64x64.
// A from pre-split bf16 hi/lo planes: row (eA*M+m), k stride Kpad (zero-padded).
// B packed u32: BMODE 0 plain [n][Kpad]; 1 gather [Ci,B,H,W]; 2 gather [B,Ci,H,W].
// z: expert chunk = bz/zpe (zpe chunks per expert; FCs pass zpe=gridDim.z -> e=0).
// Products: al*bh + ah*bl + ah*bh, fp32 acc; epilogue r-scale (convs), bias
// (bz==0), fp32 atomicAdd into pre-zeroed Cout.
// ---------------------------------------------------------------------------
template<int BMODE, int BIAS, int TROUT>
__global__ __launch_bounds__(256)
void mgemm_kernel(const u16* __restrict__ Whi, const u16* __restrict__ Wlo,
                  const u32* __restrict__ Bpk, const int2* __restrict__ ktab,
                  const float* __restrict__ rptr, const float* __restrict__ bias,
                  float* __restrict__ Cout,
                  int M, int N, int Kpad, int Kchunk, int zpe,
                  int Ci, int Bsz, int H, int W, int lgS, int lgOW, int stride)
{
    __shared__ __align__(16) u16 Ah[128 * 40], Al[128 * 40];  // rows m, pad to 40
    __shared__ __align__(16) u32 Bp[128 * 36];                // rows n, pad to 36
    const int tid = threadIdx.x;
    const int n0 = blockIdx.x << 7, m0 = blockIdx.y << 7;
    const int bz = blockIdx.z;
    const int eA = bz / zpe;
    const int kq0 = (bz - eA * zpe) * Kchunk;

    // staging coords
    const int rowA = tid >> 1, kh16 = (tid & 1) << 4;   // A: 2 thr/row, 16 bf16 each
    const int nB = tid & 127, kOff = (tid >> 7) << 4;   // B: 16 u32 per thread

    // n-side conv indices (k-independent)
    int ohs = 0, ows = 0; long nBase = 0;
    if (BMODE != 0) {
        int nn = n0 + nB;
        int bB = nn >> lgS;
        int sidx = nn & ((1 << lgS) - 1);
        ohs = (sidx >> lgOW) * stride - 1;
        ows = (sidx & ((1 << lgOW) - 1)) * stride - 1;
        long bOff = (BMODE == 2) ? (long)bB * Ci * H * W : (long)bB * H * W;
        nBase = bOff + (long)ohs * W + ows;
    }

    const int lane = tid & 63, wv = tid >> 6;
    const int lm = lane & 15, qd = lane >> 4;
    const int wm = (wv & 1) << 6, wn = (wv >> 1) << 6;

    f32x4 acc[4][4];
#pragma unroll
    for (int i = 0; i < 4; ++i)
#pragma unroll
        for (int j = 0; j < 4; ++j)
            acc[i][j] = (f32x4){0.f, 0.f, 0.f, 0.f};

    const size_t aRowBase = (size_t)eA * M;

    for (int kq = kq0; kq < kq0 + Kchunk; kq += 32) {
        // ---- stage A: pure vector copies from pre-split planes ----
        {
            int mg = m0 + rowA;
            uint4 h0 = {0,0,0,0}, h1 = {0,0,0,0}, l0 = {0,0,0,0}, l1 = {0,0,0,0};
            if (mg < M) {
                const u16* hp = Whi + (aRowBase + mg) * Kpad + kq + kh16;
                const u16* lp = Wlo + (aRowBase + mg) * Kpad + kq + kh16;
                h0 = *(const uint4*)hp; h1 = *(const uint4*)(hp + 8);
                l0 = *(const uint4*)lp; l1 = *(const uint4*)(lp + 8);
            }
            *(uint4*)(&Ah[rowA * 40 + kh16])     = h0;
            *(uint4*)(&Ah[rowA * 40 + kh16 + 8]) = h1;
            *(uint4*)(&Al[rowA * 40 + kh16])     = l0;
            *(uint4*)(&Al[rowA * 40 + kh16 + 8]) = l1;
        }
        // ---- stage B: packed u32, no repack ----
        if (BMODE == 0) {
            const u32* bp = Bpk + (size_t)(n0 + nB) * Kpad + kq + kOff;
            uint4 q0 = *(const uint4*)bp;
            uint4 q1 = *(const uint4*)(bp + 4);
            uint4 q2 = *(const uint4*)(bp + 8);
            uint4 q3 = *(const uint4*)(bp + 12);
            *(uint4*)(&Bp[nB * 36 + kOff])      = q0;
            *(uint4*)(&Bp[nB * 36 + kOff + 4])  = q1;
            *(uint4*)(&Bp[nB * 36 + kOff + 8])  = q2;
            *(uint4*)(&Bp[nB * 36 + kOff + 12]) = q3;
        } else {
            u32 qv[16];
#pragma unroll
            for (int j = 0; j < 16; ++j) {
                int kkG = eA * Kpad + kq + kOff + j;
                int2 t = ktab[kkG];
                int ih = ohs + (t.y >> 4), iw = ows + ((t.y >> 2) & 3);
                u32 p = 0;
                if ((unsigned)ih < (unsigned)H && (unsigned)iw < (unsigned)W)
                    p = Bpk[nBase + t.x];
                qv[j] = p;
            }
            *(uint4*)(&Bp[nB * 36 + kOff])      = make_uint4(qv[0], qv[1], qv[2], qv[3]);
            *(uint4*)(&Bp[nB * 36 + kOff + 4])  = make_uint4(qv[4], qv[5], qv[6], qv[7]);
            *(uint4*)(&Bp[nB * 36 + kOff + 8])  = make_uint4(qv[8], qv[9], qv[10], qv[11]);
            *(uint4*)(&Bp[nB * 36 + kOff + 12]) = make_uint4(qv[12], qv[13], qv[14], qv[15]);
        }
        __syncthreads();
        // ---- compute: A frags direct; B unpacked from packed LDS ----
        {
            bf16x8 ah[4], al[4];
#pragma unroll
            for (int mi = 0; mi < 4; ++mi) {
                int row = wm + mi * 16 + lm;
                ah[mi] = *(const bf16x8*)(&Ah[row * 40 + qd * 8]);
                al[mi] = *(const bf16x8*)(&Al[row * 40 + qd * 8]);
            }
#pragma unroll
            for (int ni = 0; ni < 4; ++ni) {
                int row = wn + ni * 16 + lm;
                const u32* bp = &Bp[row * 36 + qd * 8];
                uint4 p0 = *(const uint4*)bp;
                uint4 p1 = *(const uint4*)(bp + 4);
                union { u32 w[4]; bf16x8 v; } bh, bl;
                bh.w[0] = (p0.x >> 16) | (p0.y & 0xffff0000u);
                bl.w[0] = (p0.x & 0xffffu) | (p0.y << 16);
                bh.w[1] = (p0.z >> 16) | (p0.w & 0xffff0000u);
                bl.w[1] = (p0.z & 0xffffu) | (p0.w << 16);
                bh.w[2] = (p1.x >> 16) | (p1.y & 0xffff0000u);
                bl.w[2] = (p1.x & 0xffffu) | (p1.y << 16);
                bh.w[3] = (p1.z >> 16) | (p1.w & 0xffff0000u);
                bl.w[3] = (p1.z & 0xffffu) | (p1.w << 16);
#pragma unroll
                for (int mi = 0; mi < 4; ++mi) {
                    f32x4 c = acc[mi][ni];
                    c = __builtin_amdgcn_mfma_f32_16x16x32_bf16(al[mi], bh.v, c, 0, 0, 0);
                    c = __builtin_amdgcn_mfma_f32_16x16x32_bf16(ah[mi], bl.v, c, 0, 0, 0);
                    c = __builtin_amdgcn_mfma_f32_16x16x32_bf16(ah[mi], bh.v, c, 0, 0, 0);
                    acc[mi][ni] = c;
                }
            }
        }
        __syncthreads();
    }

    // ---- epilogue: r-scale (convs), bias (z0), fp32 atomicAdd ----
#pragma unroll
    for (int ni = 0; ni < 4; ++ni) {
        int n = n0 + wn + ni * 16 + lm;
        if (n >= N) continue;
        float rs = 1.f;
        if (BMODE != 0) rs = rptr[(n >> lgS) * 3 + eA];
#pragma unroll
        for (int mi = 0; mi < 4; ++mi)
#pragma unroll
            for (int r = 0; r < 4; ++r) {
                int m = m0 + wm + mi * 16 + qd * 4 + r;
                if (m >= M) continue;
                float v = acc[mi][ni][r];
                if (BMODE != 0) v *= rs;
                if (BIAS && bz == 0) v += bias[m];
                if (TROUT) atomicAdd(&Cout[(size_t)n * M + m], v);
                else       atomicAdd(&Cout[(size_t)m * N + n], v);
            }
    }
}

// elementwise fp32 -> packed bf16x2 (optional relu)
__global__ __launch_bounds__(256)
void pack_kernel(const float* __restrict__ in, u32* __restrict__ outp,
                 int count, int relu)
{
    int i = blockIdx.x * 256 + threadIdx.x;
    if (i >= count) return;
    float v = in[i];
    if (relu) v = fmaxf(v, 0.f);
    outp[i] = packsplit(v);
}

// 2x2/2 maxpool + relu, fp32 in -> packed out
template<int RELU>
__global__ __launch_bounds__(256)
void pool_pack_kernel(const float* __restrict__ in, u32* __restrict__ outp,
                      int CB, int H, int W)
{
    int OH = H >> 1, OW = W >> 1;
    int total = CB * OH * OW;
    int i = blockIdx.x * 256 + threadIdx.x;
    if (i >= total) return;
    int ow = i % OW;
    int t = i / OW;
    int oh = t % OH;
    int cb = t / OH;
    const float* p = in + ((size_t)cb * H + (oh << 1)) * W + (ow << 1);
    float v = fmaxf(fmaxf(p[0], p[1]), fmaxf(p[W], p[W + 1]));
    if (RELU) v = fmaxf(v, 0.f);
    outp[i] = packsplit(v);
}

// conv5 fp32 [256,512,4,4] --relu+pool--> packed hT [b][1024]
__global__ __launch_bounds__(256)
void pool_flatten_pack_kernel(const float* __restrict__ in, u32* __restrict__ outp)
{
    int i = blockIdx.x * 256 + threadIdx.x;
    if (i >= 512 * 1024) return;
    int b = i >> 10;
    int f = i & 1023;
    int c = f >> 2, s = f & 3;
    int oh = s >> 1, ow = s & 1;
    const float* p = in + (((size_t)c * 512 + b) * 4 + (oh << 1)) * 4 + (ow << 1);
    float v = fmaxf(fmaxf(p[0], p[1]), fmaxf(p[4], p[5]));
    outp[i] = packsplit(fmaxf(v, 0.f));
}

// FC act: fp32 [Mt][Nt] --relu--> packed transposed [Nt][Mt]
__global__ __launch_bounds__(256)
void tp_pack_kernel(const float* __restrict__ in, u32* __restrict__ outp,
                    int Mt, int Nt)
{
    __shared__ float t[32][33];
    int tx = threadIdx.x & 31, ty = threadIdx.x >> 5;
    int mB = blockIdx.x << 5, nB = blockIdx.y << 5;
#pragma unroll
    for (int i = 0; i < 4; ++i) {
        int mm = ty + i * 8;
        t[mm][tx] = in[(size_t)(mB + mm) * Nt + nB + tx];
    }
    __syncthreads();
#pragma unroll
    for (int i = 0; i < 4; ++i) {
        int nn = ty + i * 8;
        float v = fmaxf(t[tx][nn], 0.f);
        outp[(size_t)(nB + nn) * Mt + mB + tx] = packsplit(v);
    }
}

extern "C" void kernel_launch(void* const* d_in, const int* in_sizes, int n_in,
                              void* d_out, int out_size, void* d_ws, size_t ws_size,
                              hipStream_t stream)
{
    const float* x    = (const float*)d_in[0];
    const float* dw1  = (const float*)d_in[1];
    const float* rw1  = (const float*)d_in[2];
    const float* rb1  = (const float*)d_in[3];
    const float* dw2  = (const float*)d_in[4];
    const float* rw2  = (const float*)d_in[5];
    const float* rb2  = (const float*)d_in[6];
    const float* dw3  = (const float*)d_in[7];
    const float* rw3  = (const float*)d_in[8];
    const float* rb3  = (const float*)d_in[9];
    const float* cw4  = (const float*)d_in[10];
    const float* cr4w = (const float*)d_in[11];
    const float* cr4b = (const float*)d_in[12];
    const float* cw5  = (const float*)d_in[13];
    const float* cr5w = (const float*)d_in[14];
    const float* cr5b = (const float*)d_in[15];
    const float* fw1  = (const float*)d_in[16];
    const float* fb1  = (const float*)d_in[17];
    const float* fw2  = (const float*)d_in[18];
    const float* fb2  = (const float*)d_in[19];
    const float* fw3  = (const float*)d_in[20];
    const float* fb3  = (const float*)d_in[21];
    float* out = (float*)d_out;

    // workspace (float units); total ~25.4M floats ~= 102 MB
    float* ws    = (float*)d_ws;
    float* r1    = ws;
    float* r2    = r1 + 1536;
    float* r3    = r2 + 1536;
    float* r4    = r3 + 1536;
    float* r5    = r4 + 1536;
    int2*  tabs  = (int2*)(ws + 8192);
    int2*  t1    = tabs;            // 96
    int2*  t2    = tabs + 1024;     // 1728
    int2*  t3    = tabs + 4096;     // 5184
    int2*  t4    = tabs + 12288;    // 10368
    int2*  t5    = tabs + 24576;    // 6912
    float* sdesc = ws + 8192 + 65536;
    // region: fp32 out-slab at front, per-layer weight planes at the back.
    // max simultaneous: fc2 (2,097,152 slab + 16,777,216 plane floats).
    const size_t REGION = 18874368;
    float* region = sdesc + 196608;
    float* slab   = region;
    u16*   regEnd = (u16*)(region + REGION);
    u32*   P1     = (u32*)(region + REGION);   // 3,145,728 u32
    u32*   P2     = P1 + 3145728;

    // per-layer plane pointers: whi at regEnd-2*Pe, wlo at regEnd-Pe (u16 units)
    #define PLANES(Pe) regEnd - 2*(size_t)(Pe), regEnd - (size_t)(Pe)
    u16 *w1h = regEnd - 2*(size_t)6144,     *w1l = regEnd - (size_t)6144;
    u16 *w2h = regEnd - 2*(size_t)331776,   *w2l = regEnd - (size_t)331776;
    u16 *w3h = regEnd - 2*(size_t)1990656,  *w3l = regEnd - (size_t)1990656;
    u16 *w4h = regEnd - 2*(size_t)2654208,  *w4l = regEnd - (size_t)2654208;
    u16 *w5h = regEnd - 2*(size_t)1769472,  *w5l = regEnd - (size_t)1769472;
    u16 *f1h = regEnd - 2*(size_t)4194304,  *f1l = regEnd - (size_t)4194304;
    u16 *f2h = regEnd - 2*(size_t)16777216, *f2l = regEnd - (size_t)16777216;
    u16 *f3h = regEnd - 2*(size_t)409600,   *f3l = regEnd - (size_t)409600;

    u32* xpk   = P1;
    u32* a1pk  = P2;
    u32* a2pk  = P1;
    u32* c3pk  = P2;
    u32* c4pk  = P1;
    u32* hTpk  = P2;
    u32* f1pkT = P1;
    u32* f2pkT = P2;

    const int B = 512;

    // ---- decode tables + input pack ----
    ktab_kernel<<<1, 256, 0, stream>>>(t1, 32, 27, 1024, 32);
    ktab_kernel<<<7, 256, 0, stream>>>(t2, 576, 576, 32768, 8);
    ktab_kernel<<<21, 256, 0, stream>>>(t3, 1728, 1728, 8192, 4);
    ktab_kernel<<<41, 256, 0, stream>>>(t4, 3456, 3456, 8192, 4);
    ktab_kernel<<<27, 256, 0, stream>>>(t5, 2304, 2304, 8192, 4);
    pack_kernel<<<6144, 256, 0, stream>>>(x, xpk, 1572864, 0);

    // ---- Layer 1: DyRes conv 3->64, s2 p1 -> slab [64, 131072] ----
    wsplit_kernel<<<24, 256, 0, stream>>>(dw1, w1h, w1l, 6144, 27, 32);
    stats_kernel<<<B * 3, 64, 0, stream>>>(x, sdesc, B, 3, 1024, 0, 1, 0);
    routing_kernel<<<B, 64, 0, stream>>>(sdesc, rw1, rb1, r1, 3, 1);
    hipMemsetAsync(slab, 0, (size_t)64 * 131072 * 4, stream);
    mgemm_kernel<2, 0, 0><<<dim3(1024, 1, 3), 256, 0, stream>>>(
        w1h, w1l, xpk, t1, r1, nullptr, slab, 64, 131072, 32, 32, 1, 3, B, 32, 32, 8, 4, 2);
    pool_pack_kernel<1><<<8192, 256, 0, stream>>>(slab, a1pk, 64 * 512, 16, 16);

    // ---- Layer 2: DyRes conv 64->192 -> slab [192, 32768] ----
    wsplit_kernel<<<1296, 256, 0, stream>>>(dw2, w2h, w2l, 331776, 576, 576);
    stats_kernel<<<B * 64, 64, 0, stream>>>(a1pk, sdesc, B, 64, 64, 1, 1, 1);
    routing_kernel<<<B, 64, 0, stream>>>(sdesc, rw2, rb2, r2, 64, 1);
    hipMemsetAsync(slab, 0, (size_t)192 * 32768 * 4, stream);
    mgemm_kernel<1, 0, 0><<<dim3(256, 2, 3), 256, 0, stream>>>(
        w2h, w2l, a1pk, t2, r2, nullptr, slab, 192, 32768, 576, 576, 1, 64, B, 8, 8, 6, 3, 1);
    pool_pack_kernel<1><<<6144, 256, 0, stream>>>(slab, a2pk, 192 * 512, 8, 8);

    // ---- Layer 3: DyRes conv 192->384 -> slab [384, 8192] ----
    wsplit_kernel<<<7776, 256, 0, stream>>>(dw3, w3h, w3l, 1990656, 1728, 1728);
    stats_kernel<<<B * 192, 64, 0, stream>>>(a2pk, sdesc, B, 192, 16, 1, 1, 1);
    routing_kernel<<<B, 64, 0, stream>>>(sdesc, rw3, rb3, r3, 192, 1);
    hipMemsetAsync(slab, 0, (size_t)384 * 8192 * 4, stream);
    mgemm_kernel<1, 0, 0><<<dim3(64, 3, 6), 256, 0, stream>>>(
        w3h, w3l, a2pk, t3, r3, nullptr, slab, 384, 8192, 1728, 864, 2, 192, B, 4, 4, 4, 2, 1);
    pack_kernel<<<12288, 256, 0, stream>>>(slab, c3pk, 3145728, 1);

    // ---- Layer 4: CondConv 384->256 -> slab [256, 8192] ----
    wsplit_kernel<<<10368, 256, 0, stream>>>(cw4, w4h, w4l, 2654208, 3456, 3456);
    stats_kernel<<<B * 384, 64, 0, stream>>>(c3pk, sdesc, B, 384, 16, 1, 0, 1);
    routing_kernel<<<B, 64, 0, stream>>>(sdesc, cr4w, cr4b, r4, 384, 0);
    hipMemsetAsync(slab, 0, (size_t)256 * 8192 * 4, stream);
    mgemm_kernel<1, 0, 0><<<dim3(64, 2, 6), 256, 0, stream>>>(
        w4h, w4l, c3pk, t4, r4, nullptr, slab, 256, 8192, 3456, 1728, 2, 384, B, 4, 4, 4, 2, 1);
    pack_kernel<<<8192, 256, 0, stream>>>(slab, c4pk, 2097152, 1);

    // ---- Layer 5: CondConv 256->256 -> slab [256, 8192] ----
    wsplit_kernel<<<6912, 256, 0, stream>>>(cw5, w5h, w5l, 1769472, 2304, 2304);
    stats_kernel<<<B * 256, 64, 0, stream>>>(c4pk, sdesc, B, 256, 16, 1, 0, 1);
    routing_kernel<<<B, 64, 0, stream>>>(sdesc, cr5w, cr5b, r5, 256, 0);
    hipMemsetAsync(slab, 0, (size_t)256 * 8192 * 4, stream);
    mgemm_kernel<1, 0, 0><<<dim3(64, 2, 6), 256, 0, stream>>>(
        w5h, w5l, c4pk, t5, r5, nullptr, slab, 256, 8192, 2304, 1152, 2, 256, B, 4, 4, 4, 2, 1);

    // ---- relu + pool + flatten -> packed hT [512][1024] ----
    pool_flatten_pack_kernel<<<2048, 256, 0, stream>>>(slab, hTpk);

    // ---- FC1: 1024 -> 4096 ----
    wsplit_kernel<<<16384, 256, 0, stream>>>(fw1, f1h, f1l, 4194304, 1024, 1024);
    hipMemsetAsync(slab, 0, (size_t)4096 * 512 * 4, stream);
    mgemm_kernel<0, 1, 0><<<dim3(4, 32, 8), 256, 0, stream>>>(
        f1h, f1l, hTpk, nullptr, nullptr, fb1, slab, 4096, 512, 1024, 128, 8, 0, 0, 0, 0, 0, 0, 0);
    tp_pack_kernel<<<dim3(128, 16), 256, 0, stream>>>(slab, f1pkT, 4096, 512);

    // ---- FC2: 4096 -> 4096 ----
    wsplit_kernel<<<65536, 256, 0, stream>>>(fw2, f2h, f2l, 16777216, 4096, 4096);
    hipMemsetAsync(slab, 0, (size_t)4096 * 512 * 4, stream);
    mgemm_kernel<0, 1, 0><<<dim3(4, 32, 8), 256, 0, stream>>>(
        f2h, f2l, f1pkT, nullptr, nullptr, fb2, slab, 4096, 512, 4096, 512, 8, 0, 0, 0, 0, 0, 0, 0);
    tp_pack_kernel<<<dim3(128, 16), 256, 0, stream>>>(slab, f2pkT, 4096, 512);

    // ---- FC3: 4096 -> 100 -> d_out [512, 100] ----
    wsplit_kernel<<<1600, 256, 0, stream>>>(fw3, f3h, f3l, 409600, 4096, 4096);
    hipMemsetAsync(out, 0, (size_t)512 * 100 * 4, stream);
    mgemm_kernel<0, 1, 1><<<dim3(4, 1, 32), 256, 0, stream>>>(
        f3h, f3l, f2pkT, nullptr, nullptr, fb3, out, 100, 512, 4096, 128, 32, 0, 0, 0, 0, 0, 0, 0);
}